// Round 8
// baseline (271.779 us; speedup 1.0000x reference)
//
#include <hip/hip_runtime.h>
#include <cstdint>

typedef unsigned short ushort_t;
typedef short short8 __attribute__((ext_vector_type(8)));
typedef float f32x4 __attribute__((ext_vector_type(4)));
typedef float float4v __attribute__((ext_vector_type(4)));
typedef unsigned int uint2v __attribute__((ext_vector_type(2)));
typedef unsigned int uint4v __attribute__((ext_vector_type(4)));

#define DDIM 1024
#define HH 16
#define HEADK 64
#define BB 2
#define SS 2048

#if __has_builtin(__builtin_amdgcn_exp2f)
#define EXP2F(x) __builtin_amdgcn_exp2f(x)
#else
#define EXP2F(x) exp2f(x)
#endif

__device__ __forceinline__ ushort_t f2bf(float f) {
  union { float f; uint32_t u; } c; c.f = f;
  uint32_t u = c.u;
  u += 0x7fffu + ((u >> 16) & 1u);
  return (ushort_t)(u >> 16);
}

// truncation-pack two fp32 -> bf16x2 (1 v_perm). Bias cancels in l-normalization.
__device__ __forceinline__ uint32_t pkbf_trunc(float a, float b) {
  union { float f; uint32_t u; } ca, cb;
  ca.f = a; cb.f = b;
  return __builtin_amdgcn_perm(cb.u, ca.u, 0x07060302);
}

__device__ __forceinline__ uint32_t pkbf_rne(float a, float b) {
  return (uint32_t)f2bf(a) | ((uint32_t)f2bf(b) << 16);
}

__device__ __forceinline__ float bfhi2f(uint32_t u) {  // high half
  union { uint32_t u; float f; } c; c.u = u & 0xffff0000u; return c.f;
}
__device__ __forceinline__ float bflo2f(uint32_t u) {  // low half
  union { uint32_t u; float f; } c; c.u = u << 16; return c.f;
}

__device__ __forceinline__ void glds16(const ushort_t* gp, ushort_t* lp) {
  __builtin_amdgcn_global_load_lds(
      (const __attribute__((address_space(1))) uint32_t*)gp,
      (__attribute__((address_space(3))) uint32_t*)lp, 16, 0, 0);
}

// ---------------- fp32 -> bf16 convert, 3 tensors in one launch ----------------
__global__ void cvt3_kernel(const float* __restrict__ s0, ushort_t* __restrict__ d0, int n0,
                            const float* __restrict__ s1, ushort_t* __restrict__ d1, int n1,
                            const float* __restrict__ s2, ushort_t* __restrict__ d2, int n2) {
  int i = blockIdx.x * blockDim.x + threadIdx.x;
  const float* src; ushort_t* dst; int k;
  if (i < n0) { src = s0; dst = d0; k = i; }
  else if (i < n0 + n1) { src = s1; dst = d1; k = i - n0; }
  else if (i < n0 + n1 + n2) { src = s2; dst = d2; k = i - n0 - n1; }
  else return;
  float4v v = ((const float4v*)src)[k];
  uint2v o; o[0] = pkbf_rne(v[0], v[1]); o[1] = pkbf_rne(v[2], v[3]);
  ((uint2v*)dst)[k] = o;
}

// ---------------- 128x128 m97-structure QKV GEMM ----------------
// Proven 2-barrier simple loop; 32 KB LDS. XCD remap: by ≡ lin (mod 8).
// Scattered bf16 output:
//   cols 0-1023   (t=0): Q * 0.125*log2e -> qkv[0][b][h][s][k]
//   cols 1024-2047(t=1): K               -> qkv[1][b][h][s][k]
//   cols 2048-3071(t=2): V TRANSPOSED    -> qkv[2][b][h][k][s]
__global__ __launch_bounds__(256) void gemm_qkv128(
    const ushort_t* __restrict__ A, const ushort_t* __restrict__ Bm,
    const float* __restrict__ bias, ushort_t* __restrict__ Cbf) {
  constexpr int Kd = 1024;
  __shared__ ushort_t smem[128 * 64 * 2];
  ushort_t* As = smem;
  ushort_t* Bs = smem + 128 * 64;
  const int tid = threadIdx.x;
  const int wv = tid >> 6, lane = tid & 63;
  const int l15 = lane & 15, quad = lane >> 4;
  const int wm = wv >> 1, wn = wv & 1;

  const int lin = blockIdx.x + 24 * blockIdx.y;
  const int xcd = lin & 7, g = lin >> 3;          // g 0..95
  const int by = xcd + 8 * (g & 3);               // 0..31
  const int bx = g >> 2;                          // 0..23
  const int tm0 = by * 128, tn0 = bx * 128;

  f32x4 acc[4][4];
#pragma unroll
  for (int i = 0; i < 4; ++i)
#pragma unroll
    for (int j = 0; j < 4; ++j) acc[i][j] = (f32x4){0.f, 0.f, 0.f, 0.f};

  const int lrow = lane >> 3;
  const int gcb = (lane & 7) ^ lrow;

  for (int k0 = 0; k0 < Kd; k0 += 64) {
#pragma unroll
    for (int c = 0; c < 4; ++c) {
      int seg = wv * 4 + c;
      glds16(A + (size_t)(tm0 + seg * 8 + lrow) * Kd + k0 + gcb * 8,
             As + seg * 512);
    }
#pragma unroll
    for (int c = 0; c < 4; ++c) {
      int seg = wv * 4 + c;
      glds16(Bm + (size_t)(tn0 + seg * 8 + lrow) * Kd + k0 + gcb * 8,
             Bs + seg * 512);
    }
    __syncthreads();
#pragma unroll
    for (int kk = 0; kk < 64; kk += 32) {
      short8 af[4], bfr[4];
#pragma unroll
      for (int i = 0; i < 4; ++i) {
        int r = wm * 64 + i * 16 + l15;
        int cb = (kk >> 3) + quad;
        af[i] = *(const short8*)(As + r * 64 + ((cb ^ (l15 & 7)) << 3));
      }
#pragma unroll
      for (int j = 0; j < 4; ++j) {
        int r = wn * 64 + j * 16 + l15;
        int cb = (kk >> 3) + quad;
        bfr[j] = *(const short8*)(Bs + r * 64 + ((cb ^ (l15 & 7)) << 3));
      }
#pragma unroll
      for (int i = 0; i < 4; ++i)
#pragma unroll
        for (int j = 0; j < 4; ++j)
          acc[i][j] = __builtin_amdgcn_mfma_f32_16x16x32_bf16(
              af[i], bfr[j], acc[i][j], 0, 0, 0);
    }
    __syncthreads();
  }

  const int t = tn0 >> 10;
  if (t < 2) {
#pragma unroll
    for (int j = 0; j < 4; ++j) {
      int col = tn0 + wn * 64 + j * 16 + l15;
      float bv = bias[col];
      int hh = (col >> 6) & 15, kk2 = col & 63;
#pragma unroll
      for (int i = 0; i < 4; ++i) {
        int row0 = tm0 + wm * 64 + i * 16 + quad * 4;
#pragma unroll
        for (int r = 0; r < 4; ++r) {
          int row = row0 + r;
          int b = row >> 11, s = row & 2047;
          float v = acc[i][j][r] + bv;
          if (t == 0) v *= 0.18033688f;  // 0.125*log2(e)
          size_t base = (((size_t)t * BB + b) * HH + hh) * ((size_t)SS * HEADK);
          Cbf[base + (size_t)s * HEADK + kk2] = f2bf(v);
        }
      }
    }
  } else {
    __syncthreads();
#pragma unroll
    for (int j = 0; j < 4; ++j) {
      int c = wn * 64 + j * 16 + l15;
      float bv = bias[tn0 + c];
#pragma unroll
      for (int i = 0; i < 4; ++i) {
        int row0 = wm * 64 + i * 16 + quad * 4;
        uint2v dw;
        dw[0] = pkbf_rne(acc[i][j][0] + bv, acc[i][j][1] + bv);
        dw[1] = pkbf_rne(acc[i][j][2] + bv, acc[i][j][3] + bv);
        int rb = row0 >> 3;
        *(uint2v*)(&smem[c * 128 + (((rb ^ (c & 15)) << 3) | (row0 & 7))]) = dw;
      }
    }
    __syncthreads();
    const int rb2 = lane & 15;
    const int cg = lane >> 4;
#pragma unroll
    for (int it = 0; it < 8; ++it) {
      int c = wv * 32 + it * 4 + cg;
      short8 vv = *(const short8*)(&smem[c * 128 + ((rb2 ^ (c & 15)) << 3)]);
      int gcol = tn0 + c;
      int hh = (gcol >> 6) & 15, kk2 = gcol & 63;
      int grow = tm0 + rb2 * 8;
      int b = grow >> 11, s = grow & 2047;
      size_t base = (((size_t)2 * BB + b) * HH + hh) * ((size_t)SS * HEADK);
      *(short8*)(&Cbf[base + (size_t)kk2 * SS + s]) = vv;
    }
  }
}

// ---------------- fused reduce + output projection, 2-deep A pipeline ----------------
// (unchanged from round 6)
__global__ __launch_bounds__(256, 2) void gemm_proj(
    const ushort_t* __restrict__ Op0, const ushort_t* __restrict__ Op1,
    const float* __restrict__ Lp, const ushort_t* __restrict__ Bm,
    const float* __restrict__ bias, float* __restrict__ Cout) {
  constexpr int Kd = 1024;
  constexpr size_t nsL = (size_t)BB * HH * SS;
  __shared__ ushort_t smem[2 * 12288];  // 48 KB
  const int tid = threadIdx.x;
  const int wv = tid >> 6, lane = tid & 63;
  const int l15 = lane & 15, quad = lane >> 4;
  const int wm = wv >> 1, wn = wv & 1;  // 2 (M) x 2 (N) waves
  const int lrow = lane >> 3, gcb = (lane & 7) ^ lrow;

  const int lin = blockIdx.x + 16 * blockIdx.y;
  const int xcd = lin & 7, g = lin >> 3;          // g 0..63
  const int by = xcd + 8 * (g & 3);               // 0..31
  const int bx = g >> 2;                          // 0..15
  const int tm0 = by * 128, tn0 = bx * 64;

  f32x4 acc[4][2];
#pragma unroll
  for (int i = 0; i < 4; ++i)
#pragma unroll
    for (int j = 0; j < 2; ++j) acc[i][j] = (f32x4){0.f, 0.f, 0.f, 0.f};

  struct ARegs {
    uint4v ra0[2], ra1[2], rb0[2], rb1[2];
    float rl0[2], rl1[2];
  };
  ARegs sA, sB;

  auto readA = [&](int t, ARegs& S) {
#pragma unroll
    for (int c = 0; c < 2; ++c) {
      int u = tid + 256 * c;
      int row = u >> 2, cg = u & 3;
      int grw = tm0 + row;
      int ab = grw >> 11, as_ = grw & 2047;
      size_t lo = (size_t)(ab * HH + t) * SS + as_;
      size_t po = lo * 64 + cg * 16;
      S.ra0[c] = *(const uint4v*)(Op0 + po);
      S.ra1[c] = *(const uint4v*)(Op0 + po + 8);
      S.rb0[c] = *(const uint4v*)(Op1 + po);
      S.rb1[c] = *(const uint4v*)(Op1 + po + 8);
      S.rl0[c] = Lp[lo];
      S.rl1[c] = Lp[nsL + lo];
    }
  };
  auto writeA = [&](const ARegs& S, int pp) {
    ushort_t* As = smem + pp * 12288;
#pragma unroll
    for (int c = 0; c < 2; ++c) {
      int u = tid + 256 * c;
      int row = u >> 2, cg = u & 3;
      float inv = 1.0f / (S.rl0[c] + S.rl1[c]);
      uint4v olo, ohi;
#pragma unroll
      for (int d = 0; d < 4; ++d) {
        olo[d] = pkbf_rne((bflo2f(S.ra0[c][d]) + bflo2f(S.rb0[c][d])) * inv,
                          (bfhi2f(S.ra0[c][d]) + bfhi2f(S.rb0[c][d])) * inv);
        ohi[d] = pkbf_rne((bflo2f(S.ra1[c][d]) + bflo2f(S.rb1[c][d])) * inv,
                          (bfhi2f(S.ra1[c][d]) + bfhi2f(S.rb1[c][d])) * inv);
      }
      *(uint4v*)(&As[row * 64 + (((cg * 2) ^ (row & 7)) << 3)]) = olo;
      *(uint4v*)(&As[row * 64 + (((cg * 2 + 1) ^ (row & 7)) << 3)]) = ohi;
    }
  };
  auto stageB = [&](int t, int pp) {
    ushort_t* Bs = smem + pp * 12288 + 8192;
#pragma unroll
    for (int c = 0; c < 2; ++c) {
      int seg = wv * 2 + c;  // 8 segs x 8 rows = 64 rows
      glds16(Bm + (size_t)(tn0 + seg * 8 + lrow) * Kd + t * 64 + gcb * 8,
             Bs + seg * 512);
    }
  };

  // prologue. FIFO (oldest->newest): A0(12), B0(2), A1(12)
  readA(0, sA);
  __builtin_amdgcn_sched_barrier(0);
  stageB(0, 0);
  __builtin_amdgcn_sched_barrier(0);
  readA(1, sB);
  __builtin_amdgcn_sched_barrier(0);
  asm volatile("s_waitcnt vmcnt(14)" ::: "memory");  // A0 done (B0+A1 left)
  writeA(sA, 0);
  asm volatile("s_waitcnt lgkmcnt(0)" ::: "memory");
  asm volatile("s_waitcnt vmcnt(12)" ::: "memory");  // B0 done (A1 left)
  __builtin_amdgcn_s_barrier();
  __builtin_amdgcn_sched_barrier(0);

#pragma unroll
  for (int t = 0; t < 16; ++t) {
    const int p = t & 1;
    if (t + 1 < 16) {
      stageB(t + 1, p ^ 1);
      __builtin_amdgcn_sched_barrier(0);
    }
    if (t + 2 < 16) {
      if (t & 1) readA(t + 2, sB); else readA(t + 2, sA);
      __builtin_amdgcn_sched_barrier(0);
    }

    const ushort_t* As = smem + p * 12288;
    const ushort_t* Bs = As + 8192;
    short8 bfr[2][2], af[4][2];
#pragma unroll
    for (int j = 0; j < 2; ++j)
#pragma unroll
      for (int kc = 0; kc < 2; ++kc) {
        int n = wn * 32 + j * 16 + l15;
        bfr[j][kc] =
            *(const short8*)(Bs + n * 64 + (((kc * 4 + quad) ^ (l15 & 7)) << 3));
      }
#pragma unroll
    for (int mi = 0; mi < 4; ++mi)
#pragma unroll
      for (int kc = 0; kc < 2; ++kc) {
        int r = wm * 64 + mi * 16 + l15;
        af[mi][kc] =
            *(const short8*)(As + r * 64 + (((kc * 4 + quad) ^ (l15 & 7)) << 3));
      }
    __builtin_amdgcn_s_setprio(1);
#pragma unroll
    for (int kc = 0; kc < 2; ++kc)
#pragma unroll
      for (int mi = 0; mi < 4; ++mi)
#pragma unroll
        for (int j = 0; j < 2; ++j)
          acc[mi][j] = __builtin_amdgcn_mfma_f32_16x16x32_bf16(
              af[mi][kc], bfr[j][kc], acc[mi][j], 0, 0, 0);
    __builtin_amdgcn_s_setprio(0);

    if (t + 1 < 16) {
      if (t < 14)
        asm volatile("s_waitcnt vmcnt(14)" ::: "memory");  // A(t+1) done
      else
        asm volatile("s_waitcnt vmcnt(2)" ::: "memory");
      if (t & 1) writeA(sA, p ^ 1); else writeA(sB, p ^ 1);
      asm volatile("s_waitcnt lgkmcnt(0)" ::: "memory");
      if (t < 14)
        asm volatile("s_waitcnt vmcnt(12)" ::: "memory");  // B(t+1) done
      else
        asm volatile("s_waitcnt vmcnt(0)" ::: "memory");
      __builtin_amdgcn_s_barrier();
      __builtin_amdgcn_sched_barrier(0);
    }
  }

#pragma unroll
  for (int j = 0; j < 2; ++j) {
    int col = tn0 + wn * 32 + j * 16 + l15;
    float bv = bias[col];
#pragma unroll
    for (int mi = 0; mi < 4; ++mi) {
      int row0 = tm0 + wm * 64 + mi * 16 + quad * 4;
#pragma unroll
      for (int r = 0; r < 4; ++r)
        Cout[(size_t)(row0 + r) * 1024 + col] = acc[mi][j][r] + bv;
    }
  }
}

// ---------------- flash attention, BARRIER-FREE (K/V fragments from global) ----------------
// XCD remap keeps each (h,b,ns) K/V panel (256 KB) L2-resident (verified:
// FETCH 69.7 -> 12.3 MB). All 4 waves read IDENTICAL K/V fragments (addresses
// independent of wv) -> per-iter working set 8 KB/block is L1-resident. So
// LDS staging + the per-tile vmcnt(0)+double-barrier lockstep (the measured
// 68%-idle) buys nothing: read fragments straight from global (bit-identical
// to the staged+swizzled reads), K double-buffered in regs (loaded 1 iter
// ahead), V loaded at iter top (~400cy slack to PV). ZERO barriers in kernel.
// P stays in per-wave LDS (same-wave DS ordering). T15 P ping-pong kept:
// iter j computes QK(j+1)->P((j+1)&1) then PV(j) from P(j&1).
template <int NSPLIT>
__global__ __launch_bounds__(256, 4) void attn_kernel(
    const ushort_t* __restrict__ qkv, ushort_t* __restrict__ O0,
    ushort_t* __restrict__ O1, float* __restrict__ Lp) {
  constexpr int NT = (SS / NSPLIT) / 32;  // KV tiles per block
  __shared__ ushort_t Pw[4][2][32 * 32];  // per-wave P ping-pong; epilogue slab

  const int lin = blockIdx.x + 16 * (blockIdx.y + 16 * blockIdx.z);
  const int xcd = lin & 7, ii = lin >> 3;
  const int qt = ii & 15;
  const int hz = (ii >> 4) * 8 + xcd;     // 0..63, lin%8 fixed per hz
  const int h = hz & 15;
  const int z = hz >> 4;                  // 0..3
  const int b = z >> 1, ns = z & 1;
  const int tid = threadIdx.x;
  const int wv = tid >> 6, lane = tid & 63;
  const int l15 = lane & 15, quad = lane >> 4;

  const size_t hstride = (size_t)SS * HEADK;
  const ushort_t* Qg = qkv + ((size_t)(0 * BB + b) * HH + h) * hstride;
  const ushort_t* Kg = qkv + ((size_t)(1 * BB + b) * HH + h) * hstride;
  const ushort_t* Vg = qkv + ((size_t)(2 * BB + b) * HH + h) * hstride; // [64][2048]
  ushort_t* Opp = ns ? O1 : O0;

  short8 qf[2][2];
#pragma unroll
  for (int mi = 0; mi < 2; ++mi)
#pragma unroll
    for (int kc = 0; kc < 2; ++kc)
      qf[mi][kc] = *(const short8*)(
          Qg + (size_t)(qt * 128 + wv * 32 + mi * 16 + l15) * 64 + kc * 32 +
          quad * 8);

  const short ONE = (short)0x3F80;
  short8 ones = {ONE, ONE, ONE, ONE, ONE, ONE, ONE, ONE};

  f32x4 oat[2][4];  // O^T rows feat=cf*16+quad*4+r, col qrow=l15
  f32x4 loa[2];
#pragma unroll
  for (int mi = 0; mi < 2; ++mi) {
    loa[mi] = (f32x4){0.f, 0.f, 0.f, 0.f};
#pragma unroll
    for (int c = 0; c < 4; ++c) oat[mi][c] = (f32x4){0.f, 0.f, 0.f, 0.f};
  }

  const int pos0 = ns * (SS / NSPLIT);
  const ushort_t* Kbase = Kg + (size_t)pos0 * 64;  // K[pos][64]
  const ushort_t* Vbase = Vg + pos0;               // V[feat][SS]

  struct KSet { short8 k[2][2]; };  // [cf: pos half][feat half 0/32]
  struct VSet { short8 v[4]; };     // [cf: feat quarter]

  // kf = K[pos0+j*32 + cf*16+l15][{0,32}+quad*8 ..+8] — bit-identical to the
  // old staged+swizzled LDS reads (verified algebra).
  auto loadK = [&](int j, KSet& S) {
#pragma unroll
    for (int cf = 0; cf < 2; ++cf) {
      const ushort_t* p =
          Kbase + (size_t)(j * 32 + cf * 16 + l15) * 64 + quad * 8;
      S.k[cf][0] = *(const short8*)(p);
      S.k[cf][1] = *(const short8*)(p + 32);
    }
  };
  // vf = V[cf*16+l15][pos0+j*32+quad*8 ..+8]
  auto loadV = [&](int j, VSet& S) {
#pragma unroll
    for (int cf = 0; cf < 4; ++cf)
      S.v[cf] = *(const short8*)(Vbase + (size_t)(cf * 16 + l15) * SS +
                                 j * 32 + quad * 8);
  };

  auto qk_phase = [&](const KSet& S, int pb) {
    f32x4 st[2][2];
    __builtin_amdgcn_s_setprio(1);
#pragma unroll
    for (int cf = 0; cf < 2; ++cf)
#pragma unroll
      for (int mi = 0; mi < 2; ++mi) {
        f32x4 z2 = (f32x4){0.f, 0.f, 0.f, 0.f};
        z2 = __builtin_amdgcn_mfma_f32_16x16x32_bf16(S.k[cf][0], qf[mi][0], z2,
                                                     0, 0, 0);
        z2 = __builtin_amdgcn_mfma_f32_16x16x32_bf16(S.k[cf][1], qf[mi][1], z2,
                                                     0, 0, 0);
        st[mi][cf] = z2;
      }
    __builtin_amdgcn_s_setprio(0);
#pragma unroll
    for (int mi = 0; mi < 2; ++mi)
#pragma unroll
      for (int cf = 0; cf < 2; ++cf) {
        float e0 = EXP2F(st[mi][cf][0]);
        float e1 = EXP2F(st[mi][cf][1]);
        float e2 = EXP2F(st[mi][cf][2]);
        float e3 = EXP2F(st[mi][cf][3]);
        uint2v dw;
        dw[0] = pkbf_trunc(e0, e1);
        dw[1] = pkbf_trunc(e2, e3);
        int row = mi * 16 + l15;
        int pbv = 2 * cf + (quad >> 1);
        int pbs = pbv ^ ((l15 >> 1) & 3);
        *(uint2v*)(&Pw[wv][pb][row * 32 + pbs * 8 + (quad & 1) * 4]) = dw;
      }
  };

  auto pv_phase = [&](const VSet& S, int j) {
    short8 pa[2];
#pragma unroll
    for (int mi = 0; mi < 2; ++mi) {
      int row = mi * 16 + l15;
      pa[mi] = *(const short8*)(&Pw[wv][j & 1][row * 32 +
                                              ((quad ^ ((l15 >> 1) & 3)) << 3)]);
    }
    __builtin_amdgcn_s_setprio(1);
#pragma unroll
    for (int cf = 0; cf < 4; ++cf)
#pragma unroll
      for (int mi = 0; mi < 2; ++mi)
        oat[mi][cf] = __builtin_amdgcn_mfma_f32_16x16x32_bf16(
            S.v[cf], pa[mi], oat[mi][cf], 0, 0, 0);
#pragma unroll
    for (int mi = 0; mi < 2; ++mi)
      loa[mi] = __builtin_amdgcn_mfma_f32_16x16x32_bf16(ones, pa[mi], loa[mi],
                                                        0, 0, 0);
    __builtin_amdgcn_s_setprio(0);
  };

  KSet k0, k1;
  VSet vv;

  // prologue: QK(0) -> P(0); then k1 <- K(1)
  loadK(0, k0);
  qk_phase(k0, 0);
  loadK(1, k1);

  // main loop: 2-step parity unroll keeps K-set selection static (rule #20)
#pragma unroll 1
  for (int jj = 0; jj < NT / 2; ++jj) {
    {  // j even: consume k1 = K(j+1); prefetch K(j+2) -> k0
      const int j = 2 * jj;
      loadV(j, vv);
      int jn = (j + 2 < NT) ? (j + 2) : (NT - 1);  // clamped (harmless reload)
      loadK(jn, k0);
      __builtin_amdgcn_sched_barrier(0);
      qk_phase(k1, (j + 1) & 1);   // j+1 <= NT-1 always (NT even)
      pv_phase(vv, j);
    }
    {  // j odd: consume k0 = K(j+1); prefetch K(j+2) -> k1
      const int j = 2 * jj + 1;
      loadV(j, vv);
      int jn = (j + 2 < NT) ? (j + 2) : (NT - 1);
      loadK(jn, k1);
      __builtin_amdgcn_sched_barrier(0);
      if (j + 1 < NT) qk_phase(k0, (j + 1) & 1);  // skipped only at j=NT-1
      pv_phase(vv, j);
    }
  }

  // epilogue: unnormalized O^T -> [qrow][feat] via per-wave Pw slab (16x64)
  const size_t obase = ((size_t)b * HH + h) * SS * HEADK;
#pragma unroll
  for (int mi = 0; mi < 2; ++mi) {
#pragma unroll
    for (int cf = 0; cf < 4; ++cf) {
      uint2v dw;
      dw[0] = pkbf_rne(oat[mi][cf][0], oat[mi][cf][1]);
      dw[1] = pkbf_rne(oat[mi][cf][2], oat[mi][cf][3]);
      int cb = 2 * cf + (quad >> 1);
      int cbs = cb ^ (l15 & 7);
      *(uint2v*)(&Pw[wv][0][l15 * 64 + cbs * 8 + (quad & 1) * 4]) = dw;
    }
    const int r = lane >> 2;
#pragma unroll
    for (int pass = 0; pass < 2; ++pass) {
      int g = (lane & 3) + 4 * pass;
      short8 ov = *(const short8*)(&Pw[wv][0][r * 64 + ((g ^ (r & 7)) << 3)]);
      int qrow = qt * 128 + wv * 32 + mi * 16 + r;
      *(short8*)(&Opp[obase + (size_t)qrow * 64 + g * 8]) = ov;
    }
    if (quad == 0) {
      int qrow = qt * 128 + wv * 32 + mi * 16 + l15;
      Lp[((size_t)(ns * BB + b) * HH + h) * SS + qrow] = loa[mi][0];
    }
  }
}

extern "C" void kernel_launch(void* const* d_in, const int* in_sizes, int n_in,
                              void* d_out, int out_size, void* d_ws,
                              size_t ws_size, hipStream_t stream) {
  const float* x = (const float*)d_in[0];
  const float* Wqkv = (const float*)d_in[1];
  const float* bqkv = (const float*)d_in[2];
  const float* Wproj = (const float*)d_in[3];
  const float* bproj = (const float*)d_in[4];
  float* out = (float*)d_out;

  // Workspace plan (peak 25.2 MB):
  //   [0      .. 4.19M)  xb   (GEMM1 A)      -> reused as Op0 by attn
  //   [4.19M  .. 7.34M)  wqb  (GEMM1 B)      -> reused as Lp by attn
  //   [7.34M  .. 8.39M)  wpb  (GEMM2 B, alive throughout)
  //   [8.39M  .. 20.97M) qkvb (attn input)
  //   [20.97M .. 25.17M) Op1
  ushort_t* xb = (ushort_t*)d_ws;
  ushort_t* wqb = xb + (size_t)4096 * 1024;
  ushort_t* wpb = wqb + (size_t)3072 * 1024;
  ushort_t* qkvb = wpb + (size_t)1024 * 1024;
  ushort_t* Op1 = qkvb + (size_t)3 * BB * HH * SS * HEADK;
  ushort_t* Op0 = xb;
  float* Lp = (float*)wqb;

  const int n0 = 4096 * 1024 / 4, n1 = 3072 * 1024 / 4, n2 = 1024 * 1024 / 4;
  cvt3_kernel<<<(n0 + n1 + n2 + 255) / 256, 256, 0, stream>>>(
      x, xb, n0, Wqkv, wqb, n1, Wproj, wpb, n2);
  gemm_qkv128<<<dim3(3072 / 128, 4096 / 128), 256, 0, stream>>>(xb, wqb, bqkv,
                                                                qkvb);
  attn_kernel<2><<<dim3(16, 16, 4), 256, 0, stream>>>(qkvb, Op0, Op1, Lp);
  gemm_proj<<<dim3(1024 / 64, 4096 / 128), 256, 0, stream>>>(
      Op0, Op1, Lp, wpb, bproj, out);
}

// Round 9
// 194.097 us; speedup vs baseline: 1.4002x; 1.4002x over previous
//
#include <hip/hip_runtime.h>
#include <cstdint>

typedef unsigned short ushort_t;
typedef short short8 __attribute__((ext_vector_type(8)));
typedef float f32x4 __attribute__((ext_vector_type(4)));
typedef float float4v __attribute__((ext_vector_type(4)));
typedef unsigned int uint2v __attribute__((ext_vector_type(2)));
typedef unsigned int uint4v __attribute__((ext_vector_type(4)));

#define DDIM 1024
#define HH 16
#define HEADK 64
#define BB 2
#define SS 2048

#if __has_builtin(__builtin_amdgcn_exp2f)
#define EXP2F(x) __builtin_amdgcn_exp2f(x)
#else
#define EXP2F(x) exp2f(x)
#endif

__device__ __forceinline__ ushort_t f2bf(float f) {
  union { float f; uint32_t u; } c; c.f = f;
  uint32_t u = c.u;
  u += 0x7fffu + ((u >> 16) & 1u);
  return (ushort_t)(u >> 16);
}

// truncation-pack two fp32 -> bf16x2 (1 v_perm). Bias cancels in l-normalization.
__device__ __forceinline__ uint32_t pkbf_trunc(float a, float b) {
  union { float f; uint32_t u; } ca, cb;
  ca.f = a; cb.f = b;
  return __builtin_amdgcn_perm(cb.u, ca.u, 0x07060302);
}

__device__ __forceinline__ uint32_t pkbf_rne(float a, float b) {
  return (uint32_t)f2bf(a) | ((uint32_t)f2bf(b) << 16);
}

__device__ __forceinline__ float bfhi2f(uint32_t u) {  // high half
  union { uint32_t u; float f; } c; c.u = u & 0xffff0000u; return c.f;
}
__device__ __forceinline__ float bflo2f(uint32_t u) {  // low half
  union { uint32_t u; float f; } c; c.u = u << 16; return c.f;
}

__device__ __forceinline__ void glds16(const ushort_t* gp, ushort_t* lp) {
  __builtin_amdgcn_global_load_lds(
      (const __attribute__((address_space(1))) uint32_t*)gp,
      (__attribute__((address_space(3))) uint32_t*)lp, 16, 0, 0);
}

// ---------------- fp32 -> bf16 convert, 3 tensors in one launch ----------------
__global__ void cvt3_kernel(const float* __restrict__ s0, ushort_t* __restrict__ d0, int n0,
                            const float* __restrict__ s1, ushort_t* __restrict__ d1, int n1,
                            const float* __restrict__ s2, ushort_t* __restrict__ d2, int n2) {
  int i = blockIdx.x * blockDim.x + threadIdx.x;
  const float* src; ushort_t* dst; int k;
  if (i < n0) { src = s0; dst = d0; k = i; }
  else if (i < n0 + n1) { src = s1; dst = d1; k = i - n0; }
  else if (i < n0 + n1 + n2) { src = s2; dst = d2; k = i - n0 - n1; }
  else return;
  float4v v = ((const float4v*)src)[k];
  uint2v o; o[0] = pkbf_rne(v[0], v[1]); o[1] = pkbf_rne(v[2], v[3]);
  ((uint2v*)dst)[k] = o;
}

// ---------------- 128x128 m97-structure QKV GEMM ----------------
// Proven 2-barrier simple loop; 32 KB LDS. XCD remap: by ≡ lin (mod 8).
// Scattered bf16 output:
//   cols 0-1023   (t=0): Q * 0.125*log2e -> qkv[0][b][h][s][k]
//   cols 1024-2047(t=1): K               -> qkv[1][b][h][s][k]
//   cols 2048-3071(t=2): V TRANSPOSED    -> qkv[2][b][h][k][s]
__global__ __launch_bounds__(256) void gemm_qkv128(
    const ushort_t* __restrict__ A, const ushort_t* __restrict__ Bm,
    const float* __restrict__ bias, ushort_t* __restrict__ Cbf) {
  constexpr int Kd = 1024;
  __shared__ ushort_t smem[128 * 64 * 2];
  ushort_t* As = smem;
  ushort_t* Bs = smem + 128 * 64;
  const int tid = threadIdx.x;
  const int wv = tid >> 6, lane = tid & 63;
  const int l15 = lane & 15, quad = lane >> 4;
  const int wm = wv >> 1, wn = wv & 1;

  const int lin = blockIdx.x + 24 * blockIdx.y;
  const int xcd = lin & 7, g = lin >> 3;          // g 0..95
  const int by = xcd + 8 * (g & 3);               // 0..31
  const int bx = g >> 2;                          // 0..23
  const int tm0 = by * 128, tn0 = bx * 128;

  f32x4 acc[4][4];
#pragma unroll
  for (int i = 0; i < 4; ++i)
#pragma unroll
    for (int j = 0; j < 4; ++j) acc[i][j] = (f32x4){0.f, 0.f, 0.f, 0.f};

  const int lrow = lane >> 3;
  const int gcb = (lane & 7) ^ lrow;

  for (int k0 = 0; k0 < Kd; k0 += 64) {
#pragma unroll
    for (int c = 0; c < 4; ++c) {
      int seg = wv * 4 + c;
      glds16(A + (size_t)(tm0 + seg * 8 + lrow) * Kd + k0 + gcb * 8,
             As + seg * 512);
    }
#pragma unroll
    for (int c = 0; c < 4; ++c) {
      int seg = wv * 4 + c;
      glds16(Bm + (size_t)(tn0 + seg * 8 + lrow) * Kd + k0 + gcb * 8,
             Bs + seg * 512);
    }
    __syncthreads();
#pragma unroll
    for (int kk = 0; kk < 64; kk += 32) {
      short8 af[4], bfr[4];
#pragma unroll
      for (int i = 0; i < 4; ++i) {
        int r = wm * 64 + i * 16 + l15;
        int cb = (kk >> 3) + quad;
        af[i] = *(const short8*)(As + r * 64 + ((cb ^ (l15 & 7)) << 3));
      }
#pragma unroll
      for (int j = 0; j < 4; ++j) {
        int r = wn * 64 + j * 16 + l15;
        int cb = (kk >> 3) + quad;
        bfr[j] = *(const short8*)(Bs + r * 64 + ((cb ^ (l15 & 7)) << 3));
      }
#pragma unroll
      for (int i = 0; i < 4; ++i)
#pragma unroll
        for (int j = 0; j < 4; ++j)
          acc[i][j] = __builtin_amdgcn_mfma_f32_16x16x32_bf16(
              af[i], bfr[j], acc[i][j], 0, 0, 0);
    }
    __syncthreads();
  }

  const int t = tn0 >> 10;
  if (t < 2) {
#pragma unroll
    for (int j = 0; j < 4; ++j) {
      int col = tn0 + wn * 64 + j * 16 + l15;
      float bv = bias[col];
      int hh = (col >> 6) & 15, kk2 = col & 63;
#pragma unroll
      for (int i = 0; i < 4; ++i) {
        int row0 = tm0 + wm * 64 + i * 16 + quad * 4;
#pragma unroll
        for (int r = 0; r < 4; ++r) {
          int row = row0 + r;
          int b = row >> 11, s = row & 2047;
          float v = acc[i][j][r] + bv;
          if (t == 0) v *= 0.18033688f;  // 0.125*log2(e)
          size_t base = (((size_t)t * BB + b) * HH + hh) * ((size_t)SS * HEADK);
          Cbf[base + (size_t)s * HEADK + kk2] = f2bf(v);
        }
      }
    }
  } else {
    __syncthreads();
#pragma unroll
    for (int j = 0; j < 4; ++j) {
      int c = wn * 64 + j * 16 + l15;
      float bv = bias[tn0 + c];
#pragma unroll
      for (int i = 0; i < 4; ++i) {
        int row0 = wm * 64 + i * 16 + quad * 4;
        uint2v dw;
        dw[0] = pkbf_rne(acc[i][j][0] + bv, acc[i][j][1] + bv);
        dw[1] = pkbf_rne(acc[i][j][2] + bv, acc[i][j][3] + bv);
        int rb = row0 >> 3;
        *(uint2v*)(&smem[c * 128 + (((rb ^ (c & 15)) << 3) | (row0 & 7))]) = dw;
      }
    }
    __syncthreads();
    const int rb2 = lane & 15;
    const int cg = lane >> 4;
#pragma unroll
    for (int it = 0; it < 8; ++it) {
      int c = wv * 32 + it * 4 + cg;
      short8 vv = *(const short8*)(&smem[c * 128 + ((rb2 ^ (c & 15)) << 3)]);
      int gcol = tn0 + c;
      int hh = (gcol >> 6) & 15, kk2 = gcol & 63;
      int grow = tm0 + rb2 * 8;
      int b = grow >> 11, s = grow & 2047;
      size_t base = (((size_t)2 * BB + b) * HH + hh) * ((size_t)SS * HEADK);
      *(short8*)(&Cbf[base + (size_t)kk2 * SS + s]) = vv;
    }
  }
}

// ---------------- fused reduce + output projection, 2-deep A pipeline ----------------
// (round-7 version, unchanged)
__global__ __launch_bounds__(256, 2) void gemm_proj(
    const ushort_t* __restrict__ Op0, const ushort_t* __restrict__ Op1,
    const float* __restrict__ Lp, const ushort_t* __restrict__ Bm,
    const float* __restrict__ bias, float* __restrict__ Cout) {
  constexpr int Kd = 1024;
  constexpr size_t nsL = (size_t)BB * HH * SS;
  __shared__ ushort_t smem[2 * 12288];  // 48 KB
  const int tid = threadIdx.x;
  const int wv = tid >> 6, lane = tid & 63;
  const int l15 = lane & 15, quad = lane >> 4;
  const int wm = wv >> 1, wn = wv & 1;  // 2 (M) x 2 (N) waves
  const int lrow = lane >> 3, gcb = (lane & 7) ^ lrow;

  const int lin = blockIdx.x + 16 * blockIdx.y;
  const int xcd = lin & 7, g = lin >> 3;          // g 0..63
  const int by = xcd + 8 * (g & 3);               // 0..31
  const int bx = g >> 2;                          // 0..15
  const int tm0 = by * 128, tn0 = bx * 64;

  f32x4 acc[4][2];
#pragma unroll
  for (int i = 0; i < 4; ++i)
#pragma unroll
    for (int j = 0; j < 2; ++j) acc[i][j] = (f32x4){0.f, 0.f, 0.f, 0.f};

  struct ARegs {
    uint4v ra0[2], ra1[2], rb0[2], rb1[2];
    float rl0[2], rl1[2];
  };
  ARegs sA, sB;

  auto readA = [&](int t, ARegs& S) {
#pragma unroll
    for (int c = 0; c < 2; ++c) {
      int u = tid + 256 * c;
      int row = u >> 2, cg = u & 3;
      int grw = tm0 + row;
      int ab = grw >> 11, as_ = grw & 2047;
      size_t lo = (size_t)(ab * HH + t) * SS + as_;
      size_t po = lo * 64 + cg * 16;
      S.ra0[c] = *(const uint4v*)(Op0 + po);
      S.ra1[c] = *(const uint4v*)(Op0 + po + 8);
      S.rb0[c] = *(const uint4v*)(Op1 + po);
      S.rb1[c] = *(const uint4v*)(Op1 + po + 8);
      S.rl0[c] = Lp[lo];
      S.rl1[c] = Lp[nsL + lo];
    }
  };
  auto writeA = [&](const ARegs& S, int pp) {
    ushort_t* As = smem + pp * 12288;
#pragma unroll
    for (int c = 0; c < 2; ++c) {
      int u = tid + 256 * c;
      int row = u >> 2, cg = u & 3;
      float inv = 1.0f / (S.rl0[c] + S.rl1[c]);
      uint4v olo, ohi;
#pragma unroll
      for (int d = 0; d < 4; ++d) {
        olo[d] = pkbf_rne((bflo2f(S.ra0[c][d]) + bflo2f(S.rb0[c][d])) * inv,
                          (bfhi2f(S.ra0[c][d]) + bfhi2f(S.rb0[c][d])) * inv);
        ohi[d] = pkbf_rne((bflo2f(S.ra1[c][d]) + bflo2f(S.rb1[c][d])) * inv,
                          (bfhi2f(S.ra1[c][d]) + bfhi2f(S.rb1[c][d])) * inv);
      }
      *(uint4v*)(&As[row * 64 + (((cg * 2) ^ (row & 7)) << 3)]) = olo;
      *(uint4v*)(&As[row * 64 + (((cg * 2 + 1) ^ (row & 7)) << 3)]) = ohi;
    }
  };
  auto stageB = [&](int t, int pp) {
    ushort_t* Bs = smem + pp * 12288 + 8192;
#pragma unroll
    for (int c = 0; c < 2; ++c) {
      int seg = wv * 2 + c;  // 8 segs x 8 rows = 64 rows
      glds16(Bm + (size_t)(tn0 + seg * 8 + lrow) * Kd + t * 64 + gcb * 8,
             Bs + seg * 512);
    }
  };

  // prologue. FIFO (oldest->newest): A0(12), B0(2), A1(12)
  readA(0, sA);
  __builtin_amdgcn_sched_barrier(0);
  stageB(0, 0);
  __builtin_amdgcn_sched_barrier(0);
  readA(1, sB);
  __builtin_amdgcn_sched_barrier(0);
  asm volatile("s_waitcnt vmcnt(14)" ::: "memory");  // A0 done (B0+A1 left)
  writeA(sA, 0);
  asm volatile("s_waitcnt lgkmcnt(0)" ::: "memory");
  asm volatile("s_waitcnt vmcnt(12)" ::: "memory");  // B0 done (A1 left)
  __builtin_amdgcn_s_barrier();
  __builtin_amdgcn_sched_barrier(0);

#pragma unroll
  for (int t = 0; t < 16; ++t) {
    const int p = t & 1;
    if (t + 1 < 16) {
      stageB(t + 1, p ^ 1);
      __builtin_amdgcn_sched_barrier(0);
    }
    if (t + 2 < 16) {
      if (t & 1) readA(t + 2, sB); else readA(t + 2, sA);
      __builtin_amdgcn_sched_barrier(0);
    }

    const ushort_t* As = smem + p * 12288;
    const ushort_t* Bs = As + 8192;
    short8 bfr[2][2], af[4][2];
#pragma unroll
    for (int j = 0; j < 2; ++j)
#pragma unroll
      for (int kc = 0; kc < 2; ++kc) {
        int n = wn * 32 + j * 16 + l15;
        bfr[j][kc] =
            *(const short8*)(Bs + n * 64 + (((kc * 4 + quad) ^ (l15 & 7)) << 3));
      }
#pragma unroll
    for (int mi = 0; mi < 4; ++mi)
#pragma unroll
      for (int kc = 0; kc < 2; ++kc) {
        int r = wm * 64 + mi * 16 + l15;
        af[mi][kc] =
            *(const short8*)(As + r * 64 + (((kc * 4 + quad) ^ (l15 & 7)) << 3));
      }
    __builtin_amdgcn_s_setprio(1);
#pragma unroll
    for (int kc = 0; kc < 2; ++kc)
#pragma unroll
      for (int mi = 0; mi < 4; ++mi)
#pragma unroll
        for (int j = 0; j < 2; ++j)
          acc[mi][j] = __builtin_amdgcn_mfma_f32_16x16x32_bf16(
              af[mi][kc], bfr[j][kc], acc[mi][j], 0, 0, 0);
    __builtin_amdgcn_s_setprio(0);

    if (t + 1 < 16) {
      if (t < 14)
        asm volatile("s_waitcnt vmcnt(14)" ::: "memory");  // A(t+1) done
      else
        asm volatile("s_waitcnt vmcnt(2)" ::: "memory");
      if (t & 1) writeA(sA, p ^ 1); else writeA(sB, p ^ 1);
      asm volatile("s_waitcnt lgkmcnt(0)" ::: "memory");
      if (t < 14)
        asm volatile("s_waitcnt vmcnt(12)" ::: "memory");  // B(t+1) done
      else
        asm volatile("s_waitcnt vmcnt(0)" ::: "memory");
      __builtin_amdgcn_s_barrier();
      __builtin_amdgcn_sched_barrier(0);
    }
  }

#pragma unroll
  for (int j = 0; j < 2; ++j) {
    int col = tn0 + wn * 32 + j * 16 + l15;
    float bv = bias[col];
#pragma unroll
    for (int mi = 0; mi < 4; ++mi) {
      int row0 = tm0 + wm * 64 + mi * 16 + quad * 4;
#pragma unroll
      for (int r = 0; r < 4; ++r)
        Cout[(size_t)(row0 + r) * 1024 + col] = acc[mi][j][r] + bv;
    }
  }
}

// ---------------- flash attention, KV-split, software-pipelined ----------------
// REVERTED to the round-6 proven version (46.7-47.2 us): staged LDS K/V
// (coalesced glds16 + 4x dedup across waves — the round-7 global-fragment
// experiment showed removing this costs 2.7x), XCD remap (FETCH 69.7->12.3 MB),
// T15 P ping-pong pipeline.
template <int NSPLIT>
__global__ __launch_bounds__(256, 4) void attn_kernel(
    const ushort_t* __restrict__ qkv, ushort_t* __restrict__ O0,
    ushort_t* __restrict__ O1, float* __restrict__ Lp) {
  constexpr int NT = (SS / NSPLIT) / 32;  // KV tiles per block
  __shared__ ushort_t Kt[3][32 * 64];     // [pos32][feat64], XOR-swizzled
  __shared__ ushort_t Vt[3][64 * 32];     // [feat64][pos32], XOR-swizzled
  __shared__ ushort_t Pw[4][2][32 * 32];  // per-wave P ping-pong; epilogue slab

  const int lin = blockIdx.x + 16 * (blockIdx.y + 16 * blockIdx.z);
  const int xcd = lin & 7, ii = lin >> 3;
  const int qt = ii & 15;
  const int hz = (ii >> 4) * 8 + xcd;     // 0..63, lin%8 fixed per hz
  const int h = hz & 15;
  const int z = hz >> 4;                  // 0..3
  const int b = z >> 1, ns = z & 1;
  const int tid = threadIdx.x;
  const int wv = tid >> 6, lane = tid & 63;
  const int l15 = lane & 15, quad = lane >> 4;

  const size_t hstride = (size_t)SS * HEADK;
  const ushort_t* Qg = qkv + ((size_t)(0 * BB + b) * HH + h) * hstride;
  const ushort_t* Kg = qkv + ((size_t)(1 * BB + b) * HH + h) * hstride;
  const ushort_t* Vg = qkv + ((size_t)(2 * BB + b) * HH + h) * hstride; // [64][2048]
  ushort_t* Opp = ns ? O1 : O0;

  short8 qf[2][2];
#pragma unroll
  for (int mi = 0; mi < 2; ++mi)
#pragma unroll
    for (int kc = 0; kc < 2; ++kc)
      qf[mi][kc] = *(const short8*)(
          Qg + (size_t)(qt * 128 + wv * 32 + mi * 16 + l15) * 64 + kc * 32 +
          quad * 8);

  const short ONE = (short)0x3F80;
  short8 ones = {ONE, ONE, ONE, ONE, ONE, ONE, ONE, ONE};

  f32x4 oat[2][4];  // O^T rows feat=cf*16+quad*4+r, col qrow=l15
  f32x4 loa[2];
#pragma unroll
  for (int mi = 0; mi < 2; ++mi) {
    loa[mi] = (f32x4){0.f, 0.f, 0.f, 0.f};
#pragma unroll
    for (int c = 0; c < 4; ++c) oat[mi][c] = (f32x4){0.f, 0.f, 0.f, 0.f};
  }

  const int lrow = lane >> 3, gcb = (lane & 7) ^ lrow;   // K staging
  const int vfl = lane >> 2;                              // V staging feat 0..15
  const int vgb = (lane & 3) ^ ((vfl >> 1) & 3);          // V global pos-block

  const int pos0 = ns * (SS / NSPLIT);

  auto stage = [&](int jj, int db) {
    glds16(Kg + (size_t)(pos0 + jj * 32 + wv * 8 + lrow) * 64 + gcb * 8,
           &Kt[db][wv * 512]);
    glds16(Vg + (size_t)(wv * 16 + vfl) * SS + pos0 + jj * 32 + vgb * 8,
           &Vt[db][wv * 512]);
  };

  auto qk_phase = [&](int kb, int pb) {
    f32x4 st[2][2];
    __builtin_amdgcn_s_setprio(1);
#pragma unroll
    for (int cf = 0; cf < 2; ++cf) {
      int n = cf * 16 + l15;
      short8 kf0 = *(const short8*)(&Kt[kb][n * 64 + ((quad ^ (n & 7)) << 3)]);
      short8 kf1 =
          *(const short8*)(&Kt[kb][n * 64 + (((quad + 4) ^ (n & 7)) << 3)]);
#pragma unroll
      for (int mi = 0; mi < 2; ++mi) {
        f32x4 z2 = (f32x4){0.f, 0.f, 0.f, 0.f};
        z2 = __builtin_amdgcn_mfma_f32_16x16x32_bf16(kf0, qf[mi][0], z2, 0, 0, 0);
        z2 = __builtin_amdgcn_mfma_f32_16x16x32_bf16(kf1, qf[mi][1], z2, 0, 0, 0);
        st[mi][cf] = z2;
      }
    }
    __builtin_amdgcn_s_setprio(0);
#pragma unroll
    for (int mi = 0; mi < 2; ++mi)
#pragma unroll
      for (int cf = 0; cf < 2; ++cf) {
        float e0 = EXP2F(st[mi][cf][0]);
        float e1 = EXP2F(st[mi][cf][1]);
        float e2 = EXP2F(st[mi][cf][2]);
        float e3 = EXP2F(st[mi][cf][3]);
        uint2v dw;
        dw[0] = pkbf_trunc(e0, e1);
        dw[1] = pkbf_trunc(e2, e3);
        int row = mi * 16 + l15;
        int pbv = 2 * cf + (quad >> 1);
        int pbs = pbv ^ ((l15 >> 1) & 3);
        *(uint2v*)(&Pw[wv][pb][row * 32 + pbs * 8 + (quad & 1) * 4]) = dw;
      }
  };

  stage(0, 0);
  stage(1, 1);

  asm volatile("s_waitcnt vmcnt(2)" ::: "memory");
  __builtin_amdgcn_s_barrier();
  asm volatile("" ::: "memory");
  __builtin_amdgcn_sched_barrier(0);
  qk_phase(0, 0);

  int vb = 0;  // buffer holding tile j
  for (int j = 0; j < NT; ++j) {
    const int kb = (vb == 2) ? 0 : vb + 1;   // tile j+1
    const int sb = (kb == 2) ? 0 : kb + 1;   // tile j+2 (overwrites tile j-1)
    asm volatile("s_waitcnt vmcnt(0)" ::: "memory");
    __builtin_amdgcn_s_barrier();
    asm volatile("" ::: "memory");
    __builtin_amdgcn_sched_barrier(0);

    if (j + 2 < NT) stage(j + 2, sb);
    if (j + 1 < NT) qk_phase(kb, (j + 1) & 1);

    // PV(j): consume P written one iteration ago (same-wave DS ordering)
    short8 pa[2];
#pragma unroll
    for (int mi = 0; mi < 2; ++mi) {
      int row = mi * 16 + l15;
      pa[mi] = *(const short8*)(&Pw[wv][j & 1][row * 32 +
                                              ((quad ^ ((l15 >> 1) & 3)) << 3)]);
    }
    __builtin_amdgcn_s_setprio(1);
#pragma unroll
    for (int cf = 0; cf < 4; ++cf) {
      short8 vf = *(const short8*)(&Vt[vb][(cf * 16 + l15) * 32 +
                                           ((quad ^ ((l15 >> 1) & 3)) << 3)]);
#pragma unroll
      for (int mi = 0; mi < 2; ++mi)
        oat[mi][cf] = __builtin_amdgcn_mfma_f32_16x16x32_bf16(
            vf, pa[mi], oat[mi][cf], 0, 0, 0);
    }
#pragma unroll
    for (int mi = 0; mi < 2; ++mi)
      loa[mi] = __builtin_amdgcn_mfma_f32_16x16x32_bf16(ones, pa[mi], loa[mi],
                                                        0, 0, 0);
    __builtin_amdgcn_s_setprio(0);

    vb = kb;
  }

  // epilogue: unnormalized O^T -> [qrow][feat] via per-wave Pw slab (16x64)
  const size_t obase = ((size_t)b * HH + h) * SS * HEADK;
#pragma unroll
  for (int mi = 0; mi < 2; ++mi) {
#pragma unroll
    for (int cf = 0; cf < 4; ++cf) {
      uint2v dw;
      dw[0] = pkbf_rne(oat[mi][cf][0], oat[mi][cf][1]);
      dw[1] = pkbf_rne(oat[mi][cf][2], oat[mi][cf][3]);
      int cb = 2 * cf + (quad >> 1);
      int cbs = cb ^ (l15 & 7);
      *(uint2v*)(&Pw[wv][0][l15 * 64 + cbs * 8 + (quad & 1) * 4]) = dw;
    }
    const int r = lane >> 2;
#pragma unroll
    for (int pass = 0; pass < 2; ++pass) {
      int g = (lane & 3) + 4 * pass;
      short8 ov = *(const short8*)(&Pw[wv][0][r * 64 + ((g ^ (r & 7)) << 3)]);
      int qrow = qt * 128 + wv * 32 + mi * 16 + r;
      *(short8*)(&Opp[obase + (size_t)qrow * 64 + g * 8]) = ov;
    }
    if (quad == 0) {
      int qrow = qt * 128 + wv * 32 + mi * 16 + l15;
      Lp[((size_t)(ns * BB + b) * HH + h) * SS + qrow] = loa[mi][0];
    }
  }
}

extern "C" void kernel_launch(void* const* d_in, const int* in_sizes, int n_in,
                              void* d_out, int out_size, void* d_ws,
                              size_t ws_size, hipStream_t stream) {
  const float* x = (const float*)d_in[0];
  const float* Wqkv = (const float*)d_in[1];
  const float* bqkv = (const float*)d_in[2];
  const float* Wproj = (const float*)d_in[3];
  const float* bproj = (const float*)d_in[4];
  float* out = (float*)d_out;

  // Workspace plan (peak 25.2 MB):
  //   [0      .. 4.19M)  xb   (GEMM1 A)      -> reused as Op0 by attn
  //   [4.19M  .. 7.34M)  wqb  (GEMM1 B)      -> reused as Lp by attn
  //   [7.34M  .. 8.39M)  wpb  (GEMM2 B, alive throughout)
  //   [8.39M  .. 20.97M) qkvb (attn input)
  //   [20.97M .. 25.17M) Op1
  ushort_t* xb = (ushort_t*)d_ws;
  ushort_t* wqb = xb + (size_t)4096 * 1024;
  ushort_t* wpb = wqb + (size_t)3072 * 1024;
  ushort_t* qkvb = wpb + (size_t)1024 * 1024;
  ushort_t* Op1 = qkvb + (size_t)3 * BB * HH * SS * HEADK;
  ushort_t* Op0 = xb;
  float* Lp = (float*)wqb;

  const int n0 = 4096 * 1024 / 4, n1 = 3072 * 1024 / 4, n2 = 1024 * 1024 / 4;
  cvt3_kernel<<<(n0 + n1 + n2 + 255) / 256, 256, 0, stream>>>(
      x, xb, n0, Wqkv, wqb, n1, Wproj, wpb, n2);
  gemm_qkv128<<<dim3(3072 / 128, 4096 / 128), 256, 0, stream>>>(xb, wqb, bqkv,
                                                                qkvb);
  attn_kernel<2><<<dim3(16, 16, 4), 256, 0, stream>>>(qkvb, Op0, Op1, Lp);
  gemm_proj<<<dim3(1024 / 64, 4096 / 128), 256, 0, stream>>>(
      Op0, Op1, Lp, wpb, bproj, out);
}

// Round 11
// 188.375 us; speedup vs baseline: 1.4428x; 1.0304x over previous
//
#include <hip/hip_runtime.h>
#include <cstdint>

typedef unsigned short ushort_t;
typedef short short8 __attribute__((ext_vector_type(8)));
typedef float f32x4 __attribute__((ext_vector_type(4)));
typedef float float4v __attribute__((ext_vector_type(4)));
typedef unsigned int uint2v __attribute__((ext_vector_type(2)));

#define DDIM 1024
#define HH 16
#define HEADK 64
#define BB 2
#define SS 2048

#if __has_builtin(__builtin_amdgcn_exp2f)
#define EXP2F(x) __builtin_amdgcn_exp2f(x)
#else
#define EXP2F(x) exp2f(x)
#endif

__device__ __forceinline__ ushort_t f2bf(float f) {
  union { float f; uint32_t u; } c; c.f = f;
  uint32_t u = c.u;
  u += 0x7fffu + ((u >> 16) & 1u);
  return (ushort_t)(u >> 16);
}

// truncation-pack two fp32 -> bf16x2 (1 v_perm). Bias cancels in l-normalization.
__device__ __forceinline__ uint32_t pkbf_trunc(float a, float b) {
  union { float f; uint32_t u; } ca, cb;
  ca.f = a; cb.f = b;
  return __builtin_amdgcn_perm(cb.u, ca.u, 0x07060302);
}

__device__ __forceinline__ uint32_t pkbf_rne(float a, float b) {
  return (uint32_t)f2bf(a) | ((uint32_t)f2bf(b) << 16);
}

__device__ __forceinline__ float bfhi2f(uint32_t u) {  // high half
  union { uint32_t u; float f; } c; c.u = u & 0xffff0000u; return c.f;
}
__device__ __forceinline__ float bflo2f(uint32_t u) {  // low half
  union { uint32_t u; float f; } c; c.u = u << 16; return c.f;
}

__device__ __forceinline__ void glds16(const ushort_t* gp, ushort_t* lp) {
  __builtin_amdgcn_global_load_lds(
      (const __attribute__((address_space(1))) uint32_t*)gp,
      (__attribute__((address_space(3))) uint32_t*)lp, 16, 0, 0);
}

// ---------------- fp32 -> bf16 convert, 3 tensors in one launch ----------------
__global__ void cvt3_kernel(const float* __restrict__ s0, ushort_t* __restrict__ d0, int n0,
                            const float* __restrict__ s1, ushort_t* __restrict__ d1, int n1,
                            const float* __restrict__ s2, ushort_t* __restrict__ d2, int n2) {
  int i = blockIdx.x * blockDim.x + threadIdx.x;
  const float* src; ushort_t* dst; int k;
  if (i < n0) { src = s0; dst = d0; k = i; }
  else if (i < n0 + n1) { src = s1; dst = d1; k = i - n0; }
  else if (i < n0 + n1 + n2) { src = s2; dst = d2; k = i - n0 - n1; }
  else return;
  float4v v = ((const float4v*)src)[k];
  uint2v o; o[0] = pkbf_rne(v[0], v[1]); o[1] = pkbf_rne(v[2], v[3]);
  ((uint2v*)dst)[k] = o;
}

// ---------------- 128x128 m97-structure QKV GEMM ----------------
// Proven 2-barrier simple loop; 32 KB LDS. XCD remap: by ≡ lin (mod 8).
// Scattered bf16 output:
//   cols 0-1023   (t=0): Q * 0.125*log2e -> qkv[0][b][h][s][k]
//   cols 1024-2047(t=1): K               -> qkv[1][b][h][s][k]
//   cols 2048-3071(t=2): V TRANSPOSED    -> qkv[2][b][h][k][s]
__global__ __launch_bounds__(256) void gemm_qkv128(
    const ushort_t* __restrict__ A, const ushort_t* __restrict__ Bm,
    const float* __restrict__ bias, ushort_t* __restrict__ Cbf) {
  constexpr int Kd = 1024;
  __shared__ ushort_t smem[128 * 64 * 2];
  ushort_t* As = smem;
  ushort_t* Bs = smem + 128 * 64;
  const int tid = threadIdx.x;
  const int wv = tid >> 6, lane = tid & 63;
  const int l15 = lane & 15, quad = lane >> 4;
  const int wm = wv >> 1, wn = wv & 1;

  const int lin = blockIdx.x + 24 * blockIdx.y;
  const int xcd = lin & 7, g = lin >> 3;          // g 0..95
  const int by = xcd + 8 * (g & 3);               // 0..31
  const int bx = g >> 2;                          // 0..23
  const int tm0 = by * 128, tn0 = bx * 128;

  f32x4 acc[4][4];
#pragma unroll
  for (int i = 0; i < 4; ++i)
#pragma unroll
    for (int j = 0; j < 4; ++j) acc[i][j] = (f32x4){0.f, 0.f, 0.f, 0.f};

  const int lrow = lane >> 3;
  const int gcb = (lane & 7) ^ lrow;

  for (int k0 = 0; k0 < Kd; k0 += 64) {
#pragma unroll
    for (int c = 0; c < 4; ++c) {
      int seg = wv * 4 + c;
      glds16(A + (size_t)(tm0 + seg * 8 + lrow) * Kd + k0 + gcb * 8,
             As + seg * 512);
    }
#pragma unroll
    for (int c = 0; c < 4; ++c) {
      int seg = wv * 4 + c;
      glds16(Bm + (size_t)(tn0 + seg * 8 + lrow) * Kd + k0 + gcb * 8,
             Bs + seg * 512);
    }
    __syncthreads();
#pragma unroll
    for (int kk = 0; kk < 64; kk += 32) {
      short8 af[4], bfr[4];
#pragma unroll
      for (int i = 0; i < 4; ++i) {
        int r = wm * 64 + i * 16 + l15;
        int cb = (kk >> 3) + quad;
        af[i] = *(const short8*)(As + r * 64 + ((cb ^ (l15 & 7)) << 3));
      }
#pragma unroll
      for (int j = 0; j < 4; ++j) {
        int r = wn * 64 + j * 16 + l15;
        int cb = (kk >> 3) + quad;
        bfr[j] = *(const short8*)(Bs + r * 64 + ((cb ^ (l15 & 7)) << 3));
      }
#pragma unroll
      for (int i = 0; i < 4; ++i)
#pragma unroll
        for (int j = 0; j < 4; ++j)
          acc[i][j] = __builtin_amdgcn_mfma_f32_16x16x32_bf16(
              af[i], bfr[j], acc[i][j], 0, 0, 0);
    }
    __syncthreads();
  }

  const int t = tn0 >> 10;
  if (t < 2) {
#pragma unroll
    for (int j = 0; j < 4; ++j) {
      int col = tn0 + wn * 64 + j * 16 + l15;
      float bv = bias[col];
      int hh = (col >> 6) & 15, kk2 = col & 63;
#pragma unroll
      for (int i = 0; i < 4; ++i) {
        int row0 = tm0 + wm * 64 + i * 16 + quad * 4;
#pragma unroll
        for (int r = 0; r < 4; ++r) {
          int row = row0 + r;
          int b = row >> 11, s = row & 2047;
          float v = acc[i][j][r] + bv;
          if (t == 0) v *= 0.18033688f;  // 0.125*log2(e)
          size_t base = (((size_t)t * BB + b) * HH + hh) * ((size_t)SS * HEADK);
          Cbf[base + (size_t)s * HEADK + kk2] = f2bf(v);
        }
      }
    }
  } else {
    __syncthreads();
#pragma unroll
    for (int j = 0; j < 4; ++j) {
      int c = wn * 64 + j * 16 + l15;
      float bv = bias[tn0 + c];
#pragma unroll
      for (int i = 0; i < 4; ++i) {
        int row0 = wm * 64 + i * 16 + quad * 4;
        uint2v dw;
        dw[0] = pkbf_rne(acc[i][j][0] + bv, acc[i][j][1] + bv);
        dw[1] = pkbf_rne(acc[i][j][2] + bv, acc[i][j][3] + bv);
        int rb = row0 >> 3;
        *(uint2v*)(&smem[c * 128 + (((rb ^ (c & 15)) << 3) | (row0 & 7))]) = dw;
      }
    }
    __syncthreads();
    const int rb2 = lane & 15;
    const int cg = lane >> 4;
#pragma unroll
    for (int it = 0; it < 8; ++it) {
      int c = wv * 32 + it * 4 + cg;
      short8 vv = *(const short8*)(&smem[c * 128 + ((rb2 ^ (c & 15)) << 3)]);
      int gcol = tn0 + c;
      int hh = (gcol >> 6) & 15, kk2 = gcol & 63;
      int grow = tm0 + rb2 * 8;
      int b = grow >> 11, s = grow & 2047;
      size_t base = (((size_t)2 * BB + b) * HH + hh) * ((size_t)SS * HEADK);
      *(short8*)(&Cbf[base + (size_t)kk2 * SS + s]) = vv;
    }
  }
}

// ---------------- combine the 2 KV-split partials (round-2 proven) ----------------
__global__ void reduce_kernel(const ushort_t* __restrict__ O0,
                              const ushort_t* __restrict__ O1,
                              const float* __restrict__ Lp,
                              ushort_t* __restrict__ ob) {
  const size_t nsL = (size_t)BB * HH * SS;
  int c = blockIdx.x * blockDim.x + threadIdx.x;     // 8-elem chunk id
  int fc = c & 7;
  int hh = (c >> 3) & 15;
  int row = c >> 7;                                  // b*2048 + s
  int b = row >> 11, s = row & 2047;
  size_t po = (((size_t)b * HH + hh) * SS + s) * 64 + fc * 8;
  size_t lo = ((size_t)b * HH + hh) * SS + s;
  uint2v a0 = *(const uint2v*)(&O0[po]);
  uint2v a1 = *(const uint2v*)(&O0[po + 4]);
  uint2v b0 = *(const uint2v*)(&O1[po]);
  uint2v b1 = *(const uint2v*)(&O1[po + 4]);
  float inv = 1.0f / (Lp[lo] + Lp[nsL + lo]);
  uint2v o0, o1;
  o0[0] = pkbf_rne((bflo2f(a0[0]) + bflo2f(b0[0])) * inv,
                   (bfhi2f(a0[0]) + bfhi2f(b0[0])) * inv);
  o0[1] = pkbf_rne((bflo2f(a0[1]) + bflo2f(b0[1])) * inv,
                   (bfhi2f(a0[1]) + bfhi2f(b0[1])) * inv);
  o1[0] = pkbf_rne((bflo2f(a1[0]) + bflo2f(b1[0])) * inv,
                   (bfhi2f(a1[0]) + bfhi2f(b1[0])) * inv);
  o1[1] = pkbf_rne((bflo2f(a1[1]) + bflo2f(b1[1])) * inv,
                   (bfhi2f(a1[1]) + bfhi2f(b1[1])) * inv);
  size_t oo = ((size_t)(b * SS + s)) * DDIM + hh * 64 + fc * 8;
  *(uint2v*)(&ob[oo]) = o0;
  *(uint2v*)(&ob[oo + 4]) = o1;
}

// ---------------- output projection: 64x128 m97-structure (round-2 proven) ----------------
// C[4096,1024] fp32 = A[4096,1024]bf16 * Wproj[1024,1024]^T + bias.
// Pure glds16 staging (no reg round-trip, no in-loop normalize — the
// gemm_proj defect), 2-barrier loop, 24 KB LDS, grid 8x64=512 = 2 blocks/CU.
// XCD remap: the 8 bx sharing one A-panel (by) -> same XCD.
__global__ __launch_bounds__(256) void gemm_out(
    const ushort_t* __restrict__ A, const ushort_t* __restrict__ Bm,
    const float* __restrict__ bias, float* __restrict__ Cout) {
  constexpr int Kd = 1024;
  __shared__ ushort_t As[64 * 64];    // 8 KB
  __shared__ ushort_t Bs[128 * 64];   // 16 KB
  const int tid = threadIdx.x;
  const int wv = tid >> 6, lane = tid & 63;
  const int l15 = lane & 15, quad = lane >> 4;
  const int wm = wv >> 1, wn = wv & 1;

  // XCD remap: grid (8,64), 512 blocks; for fixed by all bx -> same XCD.
  const int lin = blockIdx.x + 8 * blockIdx.y;
  const int xcd = lin & 7, g = lin >> 3;          // g 0..63
  const int by = xcd + 8 * (g & 7);               // 0..63
  const int bx = g >> 3;                          // 0..7
  const int tm0 = by * 64, tn0 = bx * 128;

  f32x4 acc[2][4];
#pragma unroll
  for (int i = 0; i < 2; ++i)
#pragma unroll
    for (int j = 0; j < 4; ++j) acc[i][j] = (f32x4){0.f, 0.f, 0.f, 0.f};

  const int lrow = lane >> 3;
  const int gcb = (lane & 7) ^ lrow;

  for (int k0 = 0; k0 < Kd; k0 += 64) {
#pragma unroll
    for (int c = 0; c < 2; ++c) {
      int seg = wv * 2 + c;  // 8 segs x 8 rows = 64 rows
      glds16(A + (size_t)(tm0 + seg * 8 + lrow) * Kd + k0 + gcb * 8,
             As + seg * 512);
    }
#pragma unroll
    for (int c = 0; c < 4; ++c) {
      int seg = wv * 4 + c;  // 16 segs x 8 rows = 128 rows
      glds16(Bm + (size_t)(tn0 + seg * 8 + lrow) * Kd + k0 + gcb * 8,
             Bs + seg * 512);
    }
    __syncthreads();
#pragma unroll
    for (int kk = 0; kk < 64; kk += 32) {
      short8 af[2], bfr[4];
#pragma unroll
      for (int i = 0; i < 2; ++i) {
        int r = wm * 32 + i * 16 + l15;
        int cb = (kk >> 3) + quad;
        af[i] = *(const short8*)(As + r * 64 + ((cb ^ (l15 & 7)) << 3));
      }
#pragma unroll
      for (int j = 0; j < 4; ++j) {
        int r = wn * 64 + j * 16 + l15;
        int cb = (kk >> 3) + quad;
        bfr[j] = *(const short8*)(Bs + r * 64 + ((cb ^ (l15 & 7)) << 3));
      }
#pragma unroll
      for (int i = 0; i < 2; ++i)
#pragma unroll
        for (int j = 0; j < 4; ++j)
          acc[i][j] = __builtin_amdgcn_mfma_f32_16x16x32_bf16(
              af[i], bfr[j], acc[i][j], 0, 0, 0);
    }
    __syncthreads();
  }

#pragma unroll
  for (int j = 0; j < 4; ++j) {
    int col = tn0 + wn * 64 + j * 16 + l15;
    float bv = bias[col];
#pragma unroll
    for (int i = 0; i < 2; ++i) {
      int row0 = tm0 + wm * 32 + i * 16 + quad * 4;
#pragma unroll
      for (int r = 0; r < 4; ++r)
        Cout[(size_t)(row0 + r) * 1024 + col] = acc[i][j][r] + bv;
    }
  }
}

// ---------------- flash attention, KV-split, software-pipelined ----------------
// Proven round-6 version (46.7-47.2 us): staged LDS K/V (coalesced glds16 +
// 4x dedup — round-7 showed removing it costs 2.7x), XCD remap (FETCH
// 69.7->12.3 MB), T15 P ping-pong pipeline.
template <int NSPLIT>
__global__ __launch_bounds__(256, 4) void attn_kernel(
    const ushort_t* __restrict__ qkv, ushort_t* __restrict__ O0,
    ushort_t* __restrict__ O1, float* __restrict__ Lp) {
  constexpr int NT = (SS / NSPLIT) / 32;  // KV tiles per block
  __shared__ ushort_t Kt[3][32 * 64];     // [pos32][feat64], XOR-swizzled
  __shared__ ushort_t Vt[3][64 * 32];     // [feat64][pos32], XOR-swizzled
  __shared__ ushort_t Pw[4][2][32 * 32];  // per-wave P ping-pong; epilogue slab

  const int lin = blockIdx.x + 16 * (blockIdx.y + 16 * blockIdx.z);
  const int xcd = lin & 7, ii = lin >> 3;
  const int qt = ii & 15;
  const int hz = (ii >> 4) * 8 + xcd;     // 0..63, lin%8 fixed per hz
  const int h = hz & 15;
  const int z = hz >> 4;                  // 0..3
  const int b = z >> 1, ns = z & 1;
  const int tid = threadIdx.x;
  const int wv = tid >> 6, lane = tid & 63;
  const int l15 = lane & 15, quad = lane >> 4;

  const size_t hstride = (size_t)SS * HEADK;
  const ushort_t* Qg = qkv + ((size_t)(0 * BB + b) * HH + h) * hstride;
  const ushort_t* Kg = qkv + ((size_t)(1 * BB + b) * HH + h) * hstride;
  const ushort_t* Vg = qkv + ((size_t)(2 * BB + b) * HH + h) * hstride; // [64][2048]
  ushort_t* Opp = ns ? O1 : O0;

  short8 qf[2][2];
#pragma unroll
  for (int mi = 0; mi < 2; ++mi)
#pragma unroll
    for (int kc = 0; kc < 2; ++kc)
      qf[mi][kc] = *(const short8*)(
          Qg + (size_t)(qt * 128 + wv * 32 + mi * 16 + l15) * 64 + kc * 32 +
          quad * 8);

  const short ONE = (short)0x3F80;
  short8 ones = {ONE, ONE, ONE, ONE, ONE, ONE, ONE, ONE};

  f32x4 oat[2][4];  // O^T rows feat=cf*16+quad*4+r, col qrow=l15
  f32x4 loa[2];
#pragma unroll
  for (int mi = 0; mi < 2; ++mi) {
    loa[mi] = (f32x4){0.f, 0.f, 0.f, 0.f};
#pragma unroll
    for (int c = 0; c < 4; ++c) oat[mi][c] = (f32x4){0.f, 0.f, 0.f, 0.f};
  }

  const int lrow = lane >> 3, gcb = (lane & 7) ^ lrow;   // K staging
  const int vfl = lane >> 2;                              // V staging feat 0..15
  const int vgb = (lane & 3) ^ ((vfl >> 1) & 3);          // V global pos-block

  const int pos0 = ns * (SS / NSPLIT);

  auto stage = [&](int jj, int db) {
    glds16(Kg + (size_t)(pos0 + jj * 32 + wv * 8 + lrow) * 64 + gcb * 8,
           &Kt[db][wv * 512]);
    glds16(Vg + (size_t)(wv * 16 + vfl) * SS + pos0 + jj * 32 + vgb * 8,
           &Vt[db][wv * 512]);
  };

  auto qk_phase = [&](int kb, int pb) {
    f32x4 st[2][2];
    __builtin_amdgcn_s_setprio(1);
#pragma unroll
    for (int cf = 0; cf < 2; ++cf) {
      int n = cf * 16 + l15;
      short8 kf0 = *(const short8*)(&Kt[kb][n * 64 + ((quad ^ (n & 7)) << 3)]);
      short8 kf1 =
          *(const short8*)(&Kt[kb][n * 64 + (((quad + 4) ^ (n & 7)) << 3)]);
#pragma unroll
      for (int mi = 0; mi < 2; ++mi) {
        f32x4 z2 = (f32x4){0.f, 0.f, 0.f, 0.f};
        z2 = __builtin_amdgcn_mfma_f32_16x16x32_bf16(kf0, qf[mi][0], z2, 0, 0, 0);
        z2 = __builtin_amdgcn_mfma_f32_16x16x32_bf16(kf1, qf[mi][1], z2, 0, 0, 0);
        st[mi][cf] = z2;
      }
    }
    __builtin_amdgcn_s_setprio(0);
#pragma unroll
    for (int mi = 0; mi < 2; ++mi)
#pragma unroll
      for (int cf = 0; cf < 2; ++cf) {
        float e0 = EXP2F(st[mi][cf][0]);
        float e1 = EXP2F(st[mi][cf][1]);
        float e2 = EXP2F(st[mi][cf][2]);
        float e3 = EXP2F(st[mi][cf][3]);
        uint2v dw;
        dw[0] = pkbf_trunc(e0, e1);
        dw[1] = pkbf_trunc(e2, e3);
        int row = mi * 16 + l15;
        int pbv = 2 * cf + (quad >> 1);
        int pbs = pbv ^ ((l15 >> 1) & 3);
        *(uint2v*)(&Pw[wv][pb][row * 32 + pbs * 8 + (quad & 1) * 4]) = dw;
      }
  };

  stage(0, 0);
  stage(1, 1);

  asm volatile("s_waitcnt vmcnt(2)" ::: "memory");
  __builtin_amdgcn_s_barrier();
  asm volatile("" ::: "memory");
  __builtin_amdgcn_sched_barrier(0);
  qk_phase(0, 0);

  int vb = 0;  // buffer holding tile j
  for (int j = 0; j < NT; ++j) {
    const int kb = (vb == 2) ? 0 : vb + 1;   // tile j+1
    const int sb = (kb == 2) ? 0 : kb + 1;   // tile j+2 (overwrites tile j-1)
    asm volatile("s_waitcnt vmcnt(0)" ::: "memory");
    __builtin_amdgcn_s_barrier();
    asm volatile("" ::: "memory");
    __builtin_amdgcn_sched_barrier(0);

    if (j + 2 < NT) stage(j + 2, sb);
    if (j + 1 < NT) qk_phase(kb, (j + 1) & 1);

    // PV(j): consume P written one iteration ago (same-wave DS ordering)
    short8 pa[2];
#pragma unroll
    for (int mi = 0; mi < 2; ++mi) {
      int row = mi * 16 + l15;
      pa[mi] = *(const short8*)(&Pw[wv][j & 1][row * 32 +
                                              ((quad ^ ((l15 >> 1) & 3)) << 3)]);
    }
    __builtin_amdgcn_s_setprio(1);
#pragma unroll
    for (int cf = 0; cf < 4; ++cf) {
      short8 vf = *(const short8*)(&Vt[vb][(cf * 16 + l15) * 32 +
                                           ((quad ^ ((l15 >> 1) & 3)) << 3)]);
#pragma unroll
      for (int mi = 0; mi < 2; ++mi)
        oat[mi][cf] = __builtin_amdgcn_mfma_f32_16x16x32_bf16(
            vf, pa[mi], oat[mi][cf], 0, 0, 0);
    }
#pragma unroll
    for (int mi = 0; mi < 2; ++mi)
      loa[mi] = __builtin_amdgcn_mfma_f32_16x16x32_bf16(ones, pa[mi], loa[mi],
                                                        0, 0, 0);
    __builtin_amdgcn_s_setprio(0);

    vb = kb;
  }

  // epilogue: unnormalized O^T -> [qrow][feat] via per-wave Pw slab (16x64)
  const size_t obase = ((size_t)b * HH + h) * SS * HEADK;
#pragma unroll
  for (int mi = 0; mi < 2; ++mi) {
#pragma unroll
    for (int cf = 0; cf < 4; ++cf) {
      uint2v dw;
      dw[0] = pkbf_rne(oat[mi][cf][0], oat[mi][cf][1]);
      dw[1] = pkbf_rne(oat[mi][cf][2], oat[mi][cf][3]);
      int cb = 2 * cf + (quad >> 1);
      int cbs = cb ^ (l15 & 7);
      *(uint2v*)(&Pw[wv][0][l15 * 64 + cbs * 8 + (quad & 1) * 4]) = dw;
    }
    const int r = lane >> 2;
#pragma unroll
    for (int pass = 0; pass < 2; ++pass) {
      int g = (lane & 3) + 4 * pass;
      short8 ov = *(const short8*)(&Pw[wv][0][r * 64 + ((g ^ (r & 7)) << 3)]);
      int qrow = qt * 128 + wv * 32 + mi * 16 + r;
      *(short8*)(&Opp[obase + (size_t)qrow * 64 + g * 8]) = ov;
    }
    if (quad == 0) {
      int qrow = qt * 128 + wv * 32 + mi * 16 + l15;
      Lp[((size_t)(ns * BB + b) * HH + h) * SS + qrow] = loa[mi][0];
    }
  }
}

extern "C" void kernel_launch(void* const* d_in, const int* in_sizes, int n_in,
                              void* d_out, int out_size, void* d_ws,
                              size_t ws_size, hipStream_t stream) {
  const float* x = (const float*)d_in[0];
  const float* Wqkv = (const float*)d_in[1];
  const float* bqkv = (const float*)d_in[2];
  const float* Wproj = (const float*)d_in[3];
  const float* bproj = (const float*)d_in[4];
  float* out = (float*)d_out;

  // Workspace plan (peak 25.2 MB, round-2 proven):
  //   [0      .. 4.19M)  xb   (GEMM1 A)      -> reused as Op0 by attn
  //   [4.19M  .. 7.34M)  wqb  (GEMM1 B)      -> reused as Lp by attn
  //   [7.34M  .. 8.39M)  wpb  (GEMM2 B, alive throughout)
  //   [8.39M  .. 20.97M) qkvb (attn input)   -> reused as obuf by reduce
  //   [20.97M .. 25.17M) Op1
  ushort_t* xb = (ushort_t*)d_ws;
  ushort_t* wqb = xb + (size_t)4096 * 1024;
  ushort_t* wpb = wqb + (size_t)3072 * 1024;
  ushort_t* qkvb = wpb + (size_t)1024 * 1024;
  ushort_t* Op1 = qkvb + (size_t)3 * BB * HH * SS * HEADK;
  ushort_t* Op0 = xb;
  float* Lp = (float*)wqb;
  ushort_t* obuf = qkvb;

  const int n0 = 4096 * 1024 / 4, n1 = 3072 * 1024 / 4, n2 = 1024 * 1024 / 4;
  cvt3_kernel<<<(n0 + n1 + n2 + 255) / 256, 256, 0, stream>>>(
      x, xb, n0, Wqkv, wqb, n1, Wproj, wpb, n2);
  gemm_qkv128<<<dim3(3072 / 128, 4096 / 128), 256, 0, stream>>>(xb, wqb, bqkv,
                                                                qkvb);
  attn_kernel<2><<<dim3(16, 16, 4), 256, 0, stream>>>(qkvb, Op0, Op1, Lp);
  reduce_kernel<<<(BB * SS * DDIM / 8) / 256, 256, 0, stream>>>(Op0, Op1, Lp,
                                                                obuf);
  gemm_out<<<dim3(1024 / 128, 4096 / 64), 256, 0, stream>>>(obuf, wpb, bproj,
                                                            out);
}

// Round 12
// 186.245 us; speedup vs baseline: 1.4593x; 1.0114x over previous
//
#include <hip/hip_runtime.h>
#include <cstdint>

typedef unsigned short ushort_t;
typedef short short8 __attribute__((ext_vector_type(8)));
typedef float f32x4 __attribute__((ext_vector_type(4)));
typedef float float4v __attribute__((ext_vector_type(4)));
typedef unsigned int uint2v __attribute__((ext_vector_type(2)));

#define DDIM 1024
#define HH 16
#define HEADK 64
#define BB 2
#define SS 2048

#if __has_builtin(__builtin_amdgcn_exp2f)
#define EXP2F(x) __builtin_amdgcn_exp2f(x)
#else
#define EXP2F(x) exp2f(x)
#endif

__device__ __forceinline__ ushort_t f2bf(float f) {
  union { float f; uint32_t u; } c; c.f = f;
  uint32_t u = c.u;
  u += 0x7fffu + ((u >> 16) & 1u);
  return (ushort_t)(u >> 16);
}

// truncation-pack two fp32 -> bf16x2 (1 v_perm). Bias cancels in l-normalization.
__device__ __forceinline__ uint32_t pkbf_trunc(float a, float b) {
  union { float f; uint32_t u; } ca, cb;
  ca.f = a; cb.f = b;
  return __builtin_amdgcn_perm(cb.u, ca.u, 0x07060302);
}

__device__ __forceinline__ uint32_t pkbf_rne(float a, float b) {
  return (uint32_t)f2bf(a) | ((uint32_t)f2bf(b) << 16);
}

__device__ __forceinline__ float bfhi2f(uint32_t u) {  // high half
  union { uint32_t u; float f; } c; c.u = u & 0xffff0000u; return c.f;
}
__device__ __forceinline__ float bflo2f(uint32_t u) {  // low half
  union { uint32_t u; float f; } c; c.u = u << 16; return c.f;
}

__device__ __forceinline__ void glds16(const ushort_t* gp, ushort_t* lp) {
  __builtin_amdgcn_global_load_lds(
      (const __attribute__((address_space(1))) uint32_t*)gp,
      (__attribute__((address_space(3))) uint32_t*)lp, 16, 0, 0);
}

// ---------------- fp32 -> bf16 convert, 3 tensors in one launch ----------------
__global__ void cvt3_kernel(const float* __restrict__ s0, ushort_t* __restrict__ d0, int n0,
                            const float* __restrict__ s1, ushort_t* __restrict__ d1, int n1,
                            const float* __restrict__ s2, ushort_t* __restrict__ d2, int n2) {
  int i = blockIdx.x * blockDim.x + threadIdx.x;
  const float* src; ushort_t* dst; int k;
  if (i < n0) { src = s0; dst = d0; k = i; }
  else if (i < n0 + n1) { src = s1; dst = d1; k = i - n0; }
  else if (i < n0 + n1 + n2) { src = s2; dst = d2; k = i - n0 - n1; }
  else return;
  float4v v = ((const float4v*)src)[k];
  uint2v o; o[0] = pkbf_rne(v[0], v[1]); o[1] = pkbf_rne(v[2], v[3]);
  ((uint2v*)dst)[k] = o;
}

// ---------------- 256x256 QKV GEMM, 8-phase counted-vmcnt schedule ----------------
// Faithful port of the m201 template (1563 TF @4k): 8 waves (2M x 4N), BK=64,
// 128 KB LDS = [dbuf2][A/B][half2][128x64], 1 half-tile staged per phase
// (2 glds16/thread), B reg-loaded once per K-tile (12 ds_reads at q0),
// vmcnt(4) ONLY at phases 3/7 (loads span barriers; no mid-loop drain).
// Slot-liveness audit (stage >= 1 barrier after slot's last read):
//   p0/p1 stage A(t1)   -> dbuf1.A  (dead since prev iter p7 barrier)
//   p2/p3 stage B(t0+2) -> dbuf0.B  (reg-consumed at p0)
//   p4/p5 stage A(t0+2) -> dbuf0.A  (dead after p3 barrier)
//   p6/p7 stage B(t0+3) -> dbuf1.B  (reg-consumed at p4)
// vmcnt(4)@p3 confirms [B(t1)@prev-p6/7, A(t1)@p0/1] -> t1 ready for p4..p7.
// vmcnt(4)@p7 confirms t0+2 ready for next iter. Last iter: vmcnt(0) (stages gone).
// Epilogue = round-2's verified 256^2 scatter (Q*scale / K / V-transpose-slab).
// XCD remap: all 12 bx of one by-panel (A 512 KB) -> same XCD.
__global__ __launch_bounds__(512, 2) void gemm_qkv8p(
    const ushort_t* __restrict__ A, const ushort_t* __restrict__ Bm,
    const float* __restrict__ bias, ushort_t* __restrict__ Cbf) {
  __shared__ ushort_t smem[65536];  // 128 KB: slot(d,m,h) = ((d*2+m)*2+h)*8192
  const int tid = threadIdx.x;
  const int wv = tid >> 6, lane = tid & 63;
  const int l15 = lane & 15, quad = lane >> 4;
  const int wm = wv >> 2, wn = wv & 3;  // 2(M) x 4(N)
  const int lrow = lane >> 3;
  const int gcb = (lane & 7) ^ lrow;

  // XCD remap: grid (12,16) -> 192 blocks; by ≡ lin (mod 8) family.
  const int lin = blockIdx.x + 12 * blockIdx.y;
  const int xcd = lin & 7, g = lin >> 3;     // g 0..23
  const int by = xcd + 8 * (g / 12);         // 0..15
  const int bx = g % 12;                     // 0..11
  const int tm0 = by * 256, tn0 = bx * 256;

  f32x4 acc[8][4];
#pragma unroll
  for (int i = 0; i < 8; ++i)
#pragma unroll
    for (int j = 0; j < 4; ++j) acc[i][j] = (f32x4){0.f, 0.f, 0.f, 0.f};

  // stage one half-tile (128 rows x 64 cols): 2 glds16 per thread
  auto stg = [&](int t, int m, int h) {
    const ushort_t* src = m ? Bm : A;
    const int row0 = (m ? tn0 : tm0) + h * 128;
    ushort_t* dst = smem + (size_t)(((t & 1) * 2 + m) * 2 + h) * 8192;
    const int k0 = t * 64;
#pragma unroll
    for (int c = 0; c < 2; ++c) {
      int seg = wv * 2 + c;  // 16 segs x 8 rows = 128 rows
      glds16(src + (size_t)(row0 + seg * 8 + lrow) * 1024 + k0 + gcb * 8,
             dst + seg * 512);
    }
  };

  // Prologue: t0 full (4 half-tiles) + B(t1) (the "prev iter p6/p7" stages).
  stg(0, 0, 0); stg(0, 0, 1); stg(0, 1, 0); stg(0, 1, 1);
  stg(1, 1, 0); stg(1, 1, 1);
  asm volatile("s_waitcnt vmcnt(4)" ::: "memory");  // t0 landed; B(1) in flight
  __builtin_amdgcn_s_barrier();
  __builtin_amdgcn_sched_barrier(0);

  short8 bfr[4][2];
#pragma unroll 1
  for (int it = 0; it < 8; ++it) {
    const int t0 = 2 * it;
#pragma unroll
    for (int p = 0; p < 8; ++p) {
      const int d = p >> 2, q = p & 3;
      const ushort_t* Ah = smem + (size_t)(d * 4 + wm) * 8192;
      const ushort_t* Bh = smem + (size_t)(d * 4 + 2 + (wn >> 1)) * 8192;
      if (q == 0) {
#pragma unroll
        for (int j = 0; j < 4; ++j)
#pragma unroll
          for (int kc = 0; kc < 2; ++kc) {
            int n = (wn & 1) * 64 + j * 16 + l15;
            bfr[j][kc] = *(const short8*)(Bh + n * 64 +
                                          (((kc * 4 + quad) ^ (l15 & 7)) << 3));
          }
      }
      short8 af[2][2];
#pragma unroll
      for (int i2 = 0; i2 < 2; ++i2)
#pragma unroll
        for (int kc = 0; kc < 2; ++kc) {
          int r = (2 * q + i2) * 16 + l15;
          af[i2][kc] = *(const short8*)(Ah + r * 64 +
                                        (((kc * 4 + quad) ^ (l15 & 7)) << 3));
        }
      // per-phase single half-tile stage (see liveness audit above)
      if (p == 0) stg(t0 + 1, 0, 0);
      else if (p == 1) stg(t0 + 1, 0, 1);
      else if (p == 2) { if (t0 + 2 < 16) stg(t0 + 2, 1, 0); }
      else if (p == 3) { if (t0 + 2 < 16) stg(t0 + 2, 1, 1); }
      else if (p == 4) { if (t0 + 2 < 16) stg(t0 + 2, 0, 0); }
      else if (p == 5) { if (t0 + 2 < 16) stg(t0 + 2, 0, 1); }
      else if (p == 6) { if (t0 + 3 < 16) stg(t0 + 3, 1, 0); }
      else             { if (t0 + 3 < 16) stg(t0 + 3, 1, 1); }
      if (p == 3 || p == 7) {
        if (it < 7)
          asm volatile("s_waitcnt vmcnt(4)" ::: "memory");
        else
          asm volatile("s_waitcnt vmcnt(0)" ::: "memory");
      }
      __builtin_amdgcn_s_barrier();
      asm volatile("s_waitcnt lgkmcnt(0)" ::: "memory");
      __builtin_amdgcn_sched_barrier(0);
      __builtin_amdgcn_s_setprio(1);
#pragma unroll
      for (int kc = 0; kc < 2; ++kc)
#pragma unroll
        for (int i2 = 0; i2 < 2; ++i2)
#pragma unroll
          for (int j = 0; j < 4; ++j)
            acc[2 * q + i2][j] = __builtin_amdgcn_mfma_f32_16x16x32_bf16(
                af[i2][kc], bfr[j][kc], acc[2 * q + i2][j], 0, 0, 0);
      __builtin_amdgcn_s_setprio(0);
      __builtin_amdgcn_s_barrier();
    }
  }

  // ---- epilogue: round-2's verified 256^2 scatter ----
  const int tsel = tn0 >> 10;  // 0=Q 1=K 2=V (256 | 1024 boundaries)
  if (tsel < 2) {
#pragma unroll
    for (int j = 0; j < 4; ++j) {
      int col = tn0 + wn * 64 + j * 16 + l15;
      float bv = bias[col];
      int hh = (col >> 6) & 15, kk2 = col & 63;
#pragma unroll
      for (int mi = 0; mi < 8; ++mi) {
        int row0 = tm0 + wm * 128 + mi * 16 + quad * 4;
#pragma unroll
        for (int r = 0; r < 4; ++r) {
          int row = row0 + r;
          int b = row >> 11, s = row & 2047;
          float v = acc[mi][j][r] + bv;
          if (tsel == 0) v *= 0.18033688f;  // 0.125*log2(e)
          size_t base = (((size_t)tsel * BB + b) * HH + hh) * ((size_t)SS * HEADK);
          Cbf[base + (size_t)s * HEADK + kk2] = f2bf(v);
        }
      }
    }
  } else {
    // V: transpose via per-wave 16 KB LDS slab (64 cols x 128 rows)
    __builtin_amdgcn_s_barrier();  // main-loop LDS reads all complete
    ushort_t* slab = smem + wv * 8192;
#pragma unroll
    for (int j = 0; j < 4; ++j) {
      int c = j * 16 + l15;
      float bv = bias[tn0 + wn * 64 + c];
#pragma unroll
      for (int mi = 0; mi < 8; ++mi) {
        int row0 = mi * 16 + quad * 4;
        uint2v dw;
        dw[0] = pkbf_rne(acc[mi][j][0] + bv, acc[mi][j][1] + bv);
        dw[1] = pkbf_rne(acc[mi][j][2] + bv, acc[mi][j][3] + bv);
        int rb = row0 >> 3;
        *(uint2v*)(&slab[c * 128 + (((rb ^ (c & 15)) << 3) | (row0 & 7))]) = dw;
      }
    }
    // same-wave DS ops are ordered: reads below see the writes above
    const int r2 = lane & 15, cg = lane >> 4;
#pragma unroll
    for (int itv = 0; itv < 16; ++itv) {
      int c = itv * 4 + cg;  // 0..63
      short8 vv = *(const short8*)(&slab[c * 128 + ((r2 ^ (c & 15)) << 3)]);
      int gcol = tn0 + wn * 64 + c;
      int hh = (gcol >> 6) & 15, kk2 = gcol & 63;
      int grow = tm0 + wm * 128 + r2 * 8;
      int b = grow >> 11, s = grow & 2047;
      size_t base = (((size_t)2 * BB + b) * HH + hh) * ((size_t)SS * HEADK);
      *(short8*)(&Cbf[base + (size_t)kk2 * SS + s]) = vv;
    }
  }
}

// ---------------- combine the 2 KV-split partials (round-2 proven) ----------------
__global__ void reduce_kernel(const ushort_t* __restrict__ O0,
                              const ushort_t* __restrict__ O1,
                              const float* __restrict__ Lp,
                              ushort_t* __restrict__ ob) {
  const size_t nsL = (size_t)BB * HH * SS;
  int c = blockIdx.x * blockDim.x + threadIdx.x;     // 8-elem chunk id
  int fc = c & 7;
  int hh = (c >> 3) & 15;
  int row = c >> 7;                                  // b*2048 + s
  int b = row >> 11, s = row & 2047;
  size_t po = (((size_t)b * HH + hh) * SS + s) * 64 + fc * 8;
  size_t lo = ((size_t)b * HH + hh) * SS + s;
  uint2v a0 = *(const uint2v*)(&O0[po]);
  uint2v a1 = *(const uint2v*)(&O0[po + 4]);
  uint2v b0 = *(const uint2v*)(&O1[po]);
  uint2v b1 = *(const uint2v*)(&O1[po + 4]);
  float inv = 1.0f / (Lp[lo] + Lp[nsL + lo]);
  uint2v o0, o1;
  o0[0] = pkbf_rne((bflo2f(a0[0]) + bflo2f(b0[0])) * inv,
                   (bfhi2f(a0[0]) + bfhi2f(b0[0])) * inv);
  o0[1] = pkbf_rne((bflo2f(a0[1]) + bflo2f(b0[1])) * inv,
                   (bfhi2f(a0[1]) + bfhi2f(b0[1])) * inv);
  o1[0] = pkbf_rne((bflo2f(a1[0]) + bflo2f(b1[0])) * inv,
                   (bfhi2f(a1[0]) + bfhi2f(b1[0])) * inv);
  o1[1] = pkbf_rne((bflo2f(a1[1]) + bflo2f(b1[1])) * inv,
                   (bfhi2f(a1[1]) + bfhi2f(b1[1])) * inv);
  size_t oo = ((size_t)(b * SS + s)) * DDIM + hh * 64 + fc * 8;
  *(uint2v*)(&ob[oo]) = o0;
  *(uint2v*)(&ob[oo + 4]) = o1;
}

// ---------------- output projection: 64x128 m97-structure (round-2 proven) ----------------
__global__ __launch_bounds__(256) void gemm_out(
    const ushort_t* __restrict__ A, const ushort_t* __restrict__ Bm,
    const float* __restrict__ bias, float* __restrict__ Cout) {
  constexpr int Kd = 1024;
  __shared__ ushort_t As[64 * 64];    // 8 KB
  __shared__ ushort_t Bs[128 * 64];   // 16 KB
  const int tid = threadIdx.x;
  const int wv = tid >> 6, lane = tid & 63;
  const int l15 = lane & 15, quad = lane >> 4;
  const int wm = wv >> 1, wn = wv & 1;

  // XCD remap: grid (8,64), 512 blocks; for fixed by all bx -> same XCD.
  const int lin = blockIdx.x + 8 * blockIdx.y;
  const int xcd = lin & 7, g = lin >> 3;          // g 0..63
  const int by = xcd + 8 * (g & 7);               // 0..63
  const int bx = g >> 3;                          // 0..7
  const int tm0 = by * 64, tn0 = bx * 128;

  f32x4 acc[2][4];
#pragma unroll
  for (int i = 0; i < 2; ++i)
#pragma unroll
    for (int j = 0; j < 4; ++j) acc[i][j] = (f32x4){0.f, 0.f, 0.f, 0.f};

  const int lrow = lane >> 3;
  const int gcb = (lane & 7) ^ lrow;

  for (int k0 = 0; k0 < Kd; k0 += 64) {
#pragma unroll
    for (int c = 0; c < 2; ++c) {
      int seg = wv * 2 + c;  // 8 segs x 8 rows = 64 rows
      glds16(A + (size_t)(tm0 + seg * 8 + lrow) * Kd + k0 + gcb * 8,
             As + seg * 512);
    }
#pragma unroll
    for (int c = 0; c < 4; ++c) {
      int seg = wv * 4 + c;  // 16 segs x 8 rows = 128 rows
      glds16(Bm + (size_t)(tn0 + seg * 8 + lrow) * Kd + k0 + gcb * 8,
             Bs + seg * 512);
    }
    __syncthreads();
#pragma unroll
    for (int kk = 0; kk < 64; kk += 32) {
      short8 af[2], bfr[4];
#pragma unroll
      for (int i = 0; i < 2; ++i) {
        int r = wm * 32 + i * 16 + l15;
        int cb = (kk >> 3) + quad;
        af[i] = *(const short8*)(As + r * 64 + ((cb ^ (l15 & 7)) << 3));
      }
#pragma unroll
      for (int j = 0; j < 4; ++j) {
        int r = wn * 64 + j * 16 + l15;
        int cb = (kk >> 3) + quad;
        bfr[j] = *(const short8*)(Bs + r * 64 + ((cb ^ (l15 & 7)) << 3));
      }
#pragma unroll
      for (int i = 0; i < 2; ++i)
#pragma unroll
        for (int j = 0; j < 4; ++j)
          acc[i][j] = __builtin_amdgcn_mfma_f32_16x16x32_bf16(
              af[i], bfr[j], acc[i][j], 0, 0, 0);
    }
    __syncthreads();
  }

#pragma unroll
  for (int j = 0; j < 4; ++j) {
    int col = tn0 + wn * 64 + j * 16 + l15;
    float bv = bias[col];
#pragma unroll
    for (int i = 0; i < 2; ++i) {
      int row0 = tm0 + wm * 32 + i * 16 + quad * 4;
#pragma unroll
      for (int r = 0; r < 4; ++r)
        Cout[(size_t)(row0 + r) * 1024 + col] = acc[i][j][r] + bv;
    }
  }
}

// ---------------- flash attention, KV-split, software-pipelined ----------------
// Proven round-6 version (46.7-47.2 us): staged LDS K/V + XCD remap
// (FETCH 69.7->12.3 MB) + T15 P ping-pong pipeline.
template <int NSPLIT>
__global__ __launch_bounds__(256, 4) void attn_kernel(
    const ushort_t* __restrict__ qkv, ushort_t* __restrict__ O0,
    ushort_t* __restrict__ O1, float* __restrict__ Lp) {
  constexpr int NT = (SS / NSPLIT) / 32;  // KV tiles per block
  __shared__ ushort_t Kt[3][32 * 64];     // [pos32][feat64], XOR-swizzled
  __shared__ ushort_t Vt[3][64 * 32];     // [feat64][pos32], XOR-swizzled
  __shared__ ushort_t Pw[4][2][32 * 32];  // per-wave P ping-pong; epilogue slab

  const int lin = blockIdx.x + 16 * (blockIdx.y + 16 * blockIdx.z);
  const int xcd = lin & 7, ii = lin >> 3;
  const int qt = ii & 15;
  const int hz = (ii >> 4) * 8 + xcd;     // 0..63, lin%8 fixed per hz
  const int h = hz & 15;
  const int z = hz >> 4;                  // 0..3
  const int b = z >> 1, ns = z & 1;
  const int tid = threadIdx.x;
  const int wv = tid >> 6, lane = tid & 63;
  const int l15 = lane & 15, quad = lane >> 4;

  const size_t hstride = (size_t)SS * HEADK;
  const ushort_t* Qg = qkv + ((size_t)(0 * BB + b) * HH + h) * hstride;
  const ushort_t* Kg = qkv + ((size_t)(1 * BB + b) * HH + h) * hstride;
  const ushort_t* Vg = qkv + ((size_t)(2 * BB + b) * HH + h) * hstride; // [64][2048]
  ushort_t* Opp = ns ? O1 : O0;

  short8 qf[2][2];
#pragma unroll
  for (int mi = 0; mi < 2; ++mi)
#pragma unroll
    for (int kc = 0; kc < 2; ++kc)
      qf[mi][kc] = *(const short8*)(
          Qg + (size_t)(qt * 128 + wv * 32 + mi * 16 + l15) * 64 + kc * 32 +
          quad * 8);

  const short ONE = (short)0x3F80;
  short8 ones = {ONE, ONE, ONE, ONE, ONE, ONE, ONE, ONE};

  f32x4 oat[2][4];  // O^T rows feat=cf*16+quad*4+r, col qrow=l15
  f32x4 loa[2];
#pragma unroll
  for (int mi = 0; mi < 2; ++mi) {
    loa[mi] = (f32x4){0.f, 0.f, 0.f, 0.f};
#pragma unroll
    for (int c = 0; c < 4; ++c) oat[mi][c] = (f32x4){0.f, 0.f, 0.f, 0.f};
  }

  const int lrow = lane >> 3, gcb = (lane & 7) ^ lrow;   // K staging
  const int vfl = lane >> 2;                              // V staging feat 0..15
  const int vgb = (lane & 3) ^ ((vfl >> 1) & 3);          // V global pos-block

  const int pos0 = ns * (SS / NSPLIT);

  auto stage = [&](int jj, int db) {
    glds16(Kg + (size_t)(pos0 + jj * 32 + wv * 8 + lrow) * 64 + gcb * 8,
           &Kt[db][wv * 512]);
    glds16(Vg + (size_t)(wv * 16 + vfl) * SS + pos0 + jj * 32 + vgb * 8,
           &Vt[db][wv * 512]);
  };

  auto qk_phase = [&](int kb, int pb) {
    f32x4 st[2][2];
    __builtin_amdgcn_s_setprio(1);
#pragma unroll
    for (int cf = 0; cf < 2; ++cf) {
      int n = cf * 16 + l15;
      short8 kf0 = *(const short8*)(&Kt[kb][n * 64 + ((quad ^ (n & 7)) << 3)]);
      short8 kf1 =
          *(const short8*)(&Kt[kb][n * 64 + (((quad + 4) ^ (n & 7)) << 3)]);
#pragma unroll
      for (int mi = 0; mi < 2; ++mi) {
        f32x4 z2 = (f32x4){0.f, 0.f, 0.f, 0.f};
        z2 = __builtin_amdgcn_mfma_f32_16x16x32_bf16(kf0, qf[mi][0], z2, 0, 0, 0);
        z2 = __builtin_amdgcn_mfma_f32_16x16x32_bf16(kf1, qf[mi][1], z2, 0, 0, 0);
        st[mi][cf] = z2;
      }
    }
    __builtin_amdgcn_s_setprio(0);
#pragma unroll
    for (int mi = 0; mi < 2; ++mi)
#pragma unroll
      for (int cf = 0; cf < 2; ++cf) {
        float e0 = EXP2F(st[mi][cf][0]);
        float e1 = EXP2F(st[mi][cf][1]);
        float e2 = EXP2F(st[mi][cf][2]);
        float e3 = EXP2F(st[mi][cf][3]);
        uint2v dw;
        dw[0] = pkbf_trunc(e0, e1);
        dw[1] = pkbf_trunc(e2, e3);
        int row = mi * 16 + l15;
        int pbv = 2 * cf + (quad >> 1);
        int pbs = pbv ^ ((l15 >> 1) & 3);
        *(uint2v*)(&Pw[wv][pb][row * 32 + pbs * 8 + (quad & 1) * 4]) = dw;
      }
  };

  stage(0, 0);
  stage(1, 1);

  asm volatile("s_waitcnt vmcnt(2)" ::: "memory");
  __builtin_amdgcn_s_barrier();
  asm volatile("" ::: "memory");
  __builtin_amdgcn_sched_barrier(0);
  qk_phase(0, 0);

  int vb = 0;  // buffer holding tile j
  for (int j = 0; j < NT; ++j) {
    const int kb = (vb == 2) ? 0 : vb + 1;   // tile j+1
    const int sb = (kb == 2) ? 0 : kb + 1;   // tile j+2 (overwrites tile j-1)
    asm volatile("s_waitcnt vmcnt(0)" ::: "memory");
    __builtin_amdgcn_s_barrier();
    asm volatile("" ::: "memory");
    __builtin_amdgcn_sched_barrier(0);

    if (j + 2 < NT) stage(j + 2, sb);
    if (j + 1 < NT) qk_phase(kb, (j + 1) & 1);

    // PV(j): consume P written one iteration ago (same-wave DS ordering)
    short8 pa[2];
#pragma unroll
    for (int mi = 0; mi < 2; ++mi) {
      int row = mi * 16 + l15;
      pa[mi] = *(const short8*)(&Pw[wv][j & 1][row * 32 +
                                              ((quad ^ ((l15 >> 1) & 3)) << 3)]);
    }
    __builtin_amdgcn_s_setprio(1);
#pragma unroll
    for (int cf = 0; cf < 4; ++cf) {
      short8 vf = *(const short8*)(&Vt[vb][(cf * 16 + l15) * 32 +
                                           ((quad ^ ((l15 >> 1) & 3)) << 3)]);
#pragma unroll
      for (int mi = 0; mi < 2; ++mi)
        oat[mi][cf] = __builtin_amdgcn_mfma_f32_16x16x32_bf16(
            vf, pa[mi], oat[mi][cf], 0, 0, 0);
    }
#pragma unroll
    for (int mi = 0; mi < 2; ++mi)
      loa[mi] = __builtin_amdgcn_mfma_f32_16x16x32_bf16(ones, pa[mi], loa[mi],
                                                        0, 0, 0);
    __builtin_amdgcn_s_setprio(0);

    vb = kb;
  }

  // epilogue: unnormalized O^T -> [qrow][feat] via per-wave Pw slab (16x64)
  const size_t obase = ((size_t)b * HH + h) * SS * HEADK;
#pragma unroll
  for (int mi = 0; mi < 2; ++mi) {
#pragma unroll
    for (int cf = 0; cf < 4; ++cf) {
      uint2v dw;
      dw[0] = pkbf_rne(oat[mi][cf][0], oat[mi][cf][1]);
      dw[1] = pkbf_rne(oat[mi][cf][2], oat[mi][cf][3]);
      int cb = 2 * cf + (quad >> 1);
      int cbs = cb ^ (l15 & 7);
      *(uint2v*)(&Pw[wv][0][l15 * 64 + cbs * 8 + (quad & 1) * 4]) = dw;
    }
    const int r = lane >> 2;
#pragma unroll
    for (int pass = 0; pass < 2; ++pass) {
      int g = (lane & 3) + 4 * pass;
      short8 ov = *(const short8*)(&Pw[wv][0][r * 64 + ((g ^ (r & 7)) << 3)]);
      int qrow = qt * 128 + wv * 32 + mi * 16 + r;
      *(short8*)(&Opp[obase + (size_t)qrow * 64 + g * 8]) = ov;
    }
    if (quad == 0) {
      int qrow = qt * 128 + wv * 32 + mi * 16 + l15;
      Lp[((size_t)(ns * BB + b) * HH + h) * SS + qrow] = loa[mi][0];
    }
  }
}

extern "C" void kernel_launch(void* const* d_in, const int* in_sizes, int n_in,
                              void* d_out, int out_size, void* d_ws,
                              size_t ws_size, hipStream_t stream) {
  const float* x = (const float*)d_in[0];
  const float* Wqkv = (const float*)d_in[1];
  const float* bqkv = (const float*)d_in[2];
  const float* Wproj = (const float*)d_in[3];
  const float* bproj = (const float*)d_in[4];
  float* out = (float*)d_out;

  // Workspace plan (peak 25.2 MB, round-2 proven):
  //   [0      .. 4.19M)  xb   (GEMM1 A)      -> reused as Op0 by attn
  //   [4.19M  .. 7.34M)  wqb  (GEMM1 B)      -> reused as Lp by attn
  //   [7.34M  .. 8.39M)  wpb  (GEMM2 B, alive throughout)
  //   [8.39M  .. 20.97M) qkvb (attn input)   -> reused as obuf by reduce
  //   [20.97M .. 25.17M) Op1
  ushort_t* xb = (ushort_t*)d_ws;
  ushort_t* wqb = xb + (size_t)4096 * 1024;
  ushort_t* wpb = wqb + (size_t)3072 * 1024;
  ushort_t* qkvb = wpb + (size_t)1024 * 1024;
  ushort_t* Op1 = qkvb + (size_t)3 * BB * HH * SS * HEADK;
  ushort_t* Op0 = xb;
  float* Lp = (float*)wqb;
  ushort_t* obuf = qkvb;

  const int n0 = 4096 * 1024 / 4, n1 = 3072 * 1024 / 4, n2 = 1024 * 1024 / 4;
  cvt3_kernel<<<(n0 + n1 + n2 + 255) / 256, 256, 0, stream>>>(
      x, xb, n0, Wqkv, wqb, n1, Wproj, wpb, n2);
  gemm_qkv8p<<<dim3(3072 / 256, 4096 / 256), 512, 0, stream>>>(xb, wqb, bqkv,
                                                               qkvb);
  attn_kernel<2><<<dim3(16, 16, 4), 256, 0, stream>>>(qkvb, Op0, Op1, Lp);
  reduce_kernel<<<(BB * SS * DDIM / 8) / 256, 256, 0, stream>>>(Op0, Op1, Lp,
                                                                obuf);
  gemm_out<<<dim3(1024 / 128, 4096 / 64), 256, 0, stream>>>(obuf, wpb, bproj,
                                                            out);
}